// Round 11
// baseline (2934.146 us; speedup 1.0000x reference)
//
#include <hip/hip_runtime.h>

#define H_ 96
#define W_ 96
#define NV (H_ * W_)              // 9216
#define SORT_N 16384
#define NT 1024
#define NBANDS 16
#define BROWS (H_ / NBANDS)       // 6
#define BVERTS (BROWS * W_)       // 576
#define DCAP 288                  // deferred/band <= births-1 <= 287 (births = independent set <= 288)
#define NCUTS (NBANDS - 1)        // 15
#define NBE (NCUTS * W_)          // 1440
#define EV_MAX 8192

// ---- workspace layout (per image, stride 192 KiB) ----
#define WS_STRIDE (192 * 1024)
#define K_OFF     0        // u32[NV]
#define P_OFF     36864    // u16[NV]
#define PARL_OFF  55296    // u16[NV]
#define BL_OFF    73728    // u16[NV]
#define RKB_OFF   92160    // u16[2880]
#define DFR_OFF   98304    // u16[NBANDS*DCAP*3]
#define ANCH_OFF  125952   // u16[2880]
#define DCNT_OFF  131712   // u32[16]
#define BT_OFF    131776   // f64[16]
#define BS_OFF    131904   // f64[16]
#define EVR_OFF   132096   // u16[EV_MAX]
#define EVAB_OFF  148480   // u32[EV_MAX]
#define EVC_OFF   181248   // u32 evCount, u32 evM

__device__ __forceinline__ float keyToFloat(unsigned int k) {
  return __uint_as_float((k & 0x80000000u) ? (k ^ 0x80000000u) : ~k);
}

// ======================= Kernel A: load + sort + init =======================
struct SMemA {
  unsigned int   K[SORT_N];
  unsigned short P[SORT_N];
  unsigned short parL[NV];
  unsigned short BL[NV];
  unsigned short rkB[NCUTS * 192];
};

__global__ __launch_bounds__(NT, 1)
void kA(const float* __restrict__ x, unsigned char* __restrict__ ws) {
  __shared__ SMemA sm;
  const int tid = threadIdx.x;
  const float* img = x + (size_t)blockIdx.x * NV;
  unsigned char* w = ws + (size_t)blockIdx.x * WS_STRIDE;

  // P1: order-preserving keys
  for (int i = tid; i < SORT_N; i += NT) {
    if (i < NV) {
      unsigned int b = __float_as_uint(img[i]);
      sm.K[i] = b ^ ((b & 0x80000000u) ? 0xFFFFFFFFu : 0x80000000u);
      sm.P[i] = (unsigned short)i;
    } else { sm.K[i] = 0xFFFFFFFFu; sm.P[i] = 0xFFFFu; }
  }
  __syncthreads();

  // P2: bitonic sort
  for (int k = 2; k <= SORT_N; k <<= 1) {
    for (int j = k >> 1; j > 0; j >>= 1) {
      #pragma unroll 4
      for (int p = tid; p < (SORT_N / 2); p += NT) {
        int i = ((p & ~(j - 1)) << 1) | (p & (j - 1));
        int l = i | j;
        unsigned int ki = sm.K[i], kl = sm.K[l];
        unsigned short pi = sm.P[i], pl = sm.P[l];
        bool up = ((i & k) == 0);
        bool sw = up ? (ki > kl) : (ki < kl);
        sm.K[i] = sw ? kl : ki;  sm.K[l] = sw ? ki : kl;
        sm.P[i] = sw ? pl : pi;  sm.P[l] = sw ? pi : pl;
      }
      __syncthreads();
    }
  }

  // P3: parL init + boundary-row rank LUT
  for (int t = tid; t < NV; t += NT) {
    const int vid = (int)sm.P[t];
    sm.parL[vid] = (unsigned short)(0x8000u | (unsigned int)t);
    const int r = vid / W_;
    const int c = vid - r * W_;
    if ((r % BROWS) == BROWS - 1 && r < H_ - 1) sm.rkB[(r / BROWS) * 192 + c] = (unsigned short)t;
    if ((r % BROWS) == 0 && r > 0)              sm.rkB[(r / BROWS - 1) * 192 + 96 + c] = (unsigned short)t;
  }
  // P4: per-band rank lists
  {
    const int wv = tid >> 6, lane = tid & 63;
    int cnt = 0;
    for (int t0 = 0; t0 < NV; t0 += 64) {
      const int t = t0 + lane;
      const int vid = (int)sm.P[t];
      const bool mine = (vid / BVERTS) == wv;
      const unsigned long long m = __ballot(mine);
      if (mine)
        sm.BL[wv * BVERTS + cnt + __popcll(m & ((1ull << lane) - 1ull))] = (unsigned short)t;
      cnt += (int)__popcll(m);
    }
  }
  __syncthreads();

  // copy out
  unsigned int* wK = (unsigned int*)(w + K_OFF);
  for (int i = tid; i < NV; i += NT) wK[i] = sm.K[i];
  {
    unsigned int* dst = (unsigned int*)(w + P_OFF);
    const unsigned int* src = (const unsigned int*)sm.P;
    for (int i = tid; i < NV / 2; i += NT) dst[i] = src[i];
  }
  {
    unsigned int* dst = (unsigned int*)(w + PARL_OFF);
    const unsigned int* src = (const unsigned int*)sm.parL;
    for (int i = tid; i < NV / 2; i += NT) dst[i] = src[i];
  }
  {
    unsigned int* dst = (unsigned int*)(w + BL_OFF);
    const unsigned int* src = (const unsigned int*)sm.BL;
    for (int i = tid; i < NV / 2; i += NT) dst[i] = src[i];
  }
  {
    unsigned int* dst = (unsigned int*)(w + RKB_OFF);
    const unsigned int* src = (const unsigned int*)sm.rkB;
    for (int i = tid; i < (NCUTS * 192) / 2; i += NT) dst[i] = src[i];
  }
}

// ======================= Kernel B: 16-band parallel Kruskal (P5) =======================
struct SMemB {
  double bandT[16], bandS[16];
  unsigned int   K[NV];
  unsigned short P[NV];
  unsigned short parL[NV];
  unsigned short BL[NV];
  unsigned short dfr[NBANDS * DCAP * 3];
  unsigned short anchors[NCUTS * 192];
  unsigned int dcnt[16];
};

__global__ __launch_bounds__(NT, 1)
void kB(unsigned char* __restrict__ ws) {
  __shared__ SMemB sm;
  const int tid = threadIdx.x;
  unsigned char* w = ws + (size_t)blockIdx.x * WS_STRIDE;

  {
    const unsigned int* src = (const unsigned int*)(w + K_OFF);
    for (int i = tid; i < NV; i += NT) sm.K[i] = src[i];
  }
  {
    const unsigned int* src = (const unsigned int*)(w + P_OFF);
    unsigned int* dst = (unsigned int*)sm.P;
    for (int i = tid; i < NV / 2; i += NT) dst[i] = src[i];
  }
  {
    const unsigned int* src = (const unsigned int*)(w + PARL_OFF);
    unsigned int* dst = (unsigned int*)sm.parL;
    for (int i = tid; i < NV / 2; i += NT) dst[i] = src[i];
  }
  {
    const unsigned int* src = (const unsigned int*)(w + BL_OFF);
    unsigned int* dst = (unsigned int*)sm.BL;
    for (int i = tid; i < NV / 2; i += NT) dst[i] = src[i];
  }
  if (tid < 16) { sm.dcnt[tid] = 0u; sm.bandT[tid] = 0.0; sm.bandS[tid] = 0.0; }
  __syncthreads();

  if ((tid & 63) == 0) {
    const int b = tid >> 6;
    const int base = b * BVERTS;
    const int rtop = b * BROWS, rbot = rtop + BROWS - 1;
    unsigned short* db = &sm.dfr[b * DCAP * 3];
    double T = 0.0, S = 0.0;
    int dc = 0;
    int t_n = (int)sm.BL[base];
    for (int j = 0; j < BVERTS; ++j) {
      const int t = t_n;
      if (j + 1 < BVERTS) t_n = (int)sm.BL[base + j + 1];
      const int vid = (int)sm.P[t];
      const float vt = keyToFloat(sm.K[t]);
      const int r = vid / W_;
      const int c = vid - r * W_;
      int n0 = (c > 0)      ? vid - 1  : vid;
      int n1 = (c < W_ - 1) ? vid + 1  : vid;
      int n2 = (r > rtop)   ? vid - W_ : vid;
      int n3 = (r < rbot)   ? vid + W_ : vid;
      int x0 = n0, x1 = n1, x2 = n2, x3 = n3;
      unsigned int p0 = sm.parL[x0], p1 = sm.parL[x1], p2 = sm.parL[x2], p3 = sm.parL[x3];
      const unsigned int self = 0x8000u | (unsigned int)t;
      if ((p0 & 0x8000u) && (int)(p0 & 0x3FFFu) > t) { x0 = vid; n0 = vid; p0 = self; }
      if ((p1 & 0x8000u) && (int)(p1 & 0x3FFFu) > t) { x1 = vid; n1 = vid; p1 = self; }
      if ((p2 & 0x8000u) && (int)(p2 & 0x3FFFu) > t) { x2 = vid; n2 = vid; p2 = self; }
      if ((p3 & 0x8000u) && (int)(p3 & 0x3FFFu) > t) { x3 = vid; n3 = vid; p3 = self; }
      while (!((p0 & p1 & p2 & p3) & 0x8000u)) {
        x0 = (p0 & 0x8000u) ? x0 : (int)p0;
        x1 = (p1 & 0x8000u) ? x1 : (int)p1;
        x2 = (p2 & 0x8000u) ? x2 : (int)p2;
        x3 = (p3 & 0x8000u) ? x3 : (int)p3;
        p0 = sm.parL[x0]; p1 = sm.parL[x1]; p2 = sm.parL[x2]; p3 = sm.parL[x3];
      }
      const float v0 = keyToFloat(sm.K[(int)(p0 & 0x3FFFu)]);
      const float v1 = keyToFloat(sm.K[(int)(p1 & 0x3FFFu)]);
      const float v2 = keyToFloat(sm.K[(int)(p2 & 0x3FFFu)]);
      const float v3 = keyToFloat(sm.K[(int)(p3 & 0x3FFFu)]);
      int mv = vid, mr = t;
      float mval = vt;
      unsigned int mtaint = ((r == rtop && b > 0) || (r == rbot && b < NBANDS - 1)) ? 1u : 0u;
      int g0 = -1, g1 = -1, g2 = -1;
      #define DO_CHAIN(pc, xc, vc)                                              \
      {                                                                         \
        const int rr = (int)(pc & 0x3FFFu);                                     \
        const unsigned int rt = (pc >> 14) & 1u;                                \
        const int rv = xc;                                                      \
        if (rr <= t && rv != mv && rv != g0 && rv != g1 && rv != g2) {          \
          int yR, yV; unsigned int yT; float ybv;                               \
          if (rr > mr) { yR = rr; yV = rv; yT = rt; ybv = vc; }                 \
          else { yR = mr; yV = mv; yT = mtaint; ybv = mval;                     \
                 mv = rv; mr = rr; mval = vc; }                                 \
          mtaint |= rt;                                                         \
          if (yT) {                                                             \
            db[dc * 3 + 0] = (unsigned short)t;                                 \
            db[dc * 3 + 1] = (unsigned short)yR;                                \
            db[dc * 3 + 2] = (unsigned short)mr;                                \
            ++dc;                                                               \
          } else {                                                              \
            const float pers = vt - ybv;                                        \
            if (pers > 0.0f) { T += (double)pers;                               \
                               S += (double)(pers * logf(pers)); }              \
          }                                                                     \
          sm.parL[yV] = (unsigned short)mv;                                     \
          g2 = g1; g1 = g0; g0 = yV;                                            \
        }                                                                       \
      }
      DO_CHAIN(p0, x0, v0)
      DO_CHAIN(p1, x1, v1)
      DO_CHAIN(p2, x2, v2)
      DO_CHAIN(p3, x3, v3)
      #undef DO_CHAIN
      sm.parL[mv] = (unsigned short)(0x8000u | (mtaint << 14) | (unsigned int)mr);
      if (vid != mv) sm.parL[vid] = (unsigned short)mv;
      if ((int)(p0 & 0x3FFFu) <= t) { if (n0 != mv) sm.parL[n0] = (unsigned short)mv;
                                      if (x0 != mv && x0 != n0) sm.parL[x0] = (unsigned short)mv; }
      if ((int)(p1 & 0x3FFFu) <= t) { if (n1 != mv) sm.parL[n1] = (unsigned short)mv;
                                      if (x1 != mv && x1 != n1) sm.parL[x1] = (unsigned short)mv; }
      if ((int)(p2 & 0x3FFFu) <= t) { if (n2 != mv) sm.parL[n2] = (unsigned short)mv;
                                      if (x2 != mv && x2 != n2) sm.parL[x2] = (unsigned short)mv; }
      if ((int)(p3 & 0x3FFFu) <= t) { if (n3 != mv) sm.parL[n3] = (unsigned short)mv;
                                      if (x3 != mv && x3 != n3) sm.parL[x3] = (unsigned short)mv; }
      if (r == rbot && b < NBANDS - 1) sm.anchors[b * 192 + c] = (unsigned short)mr;
      if (r == rtop && b > 0)          sm.anchors[(b - 1) * 192 + 96 + c] = (unsigned short)mr;
    }
    sm.bandT[b] = T; sm.bandS[b] = S; sm.dcnt[b] = (unsigned int)dc;
  }
  __syncthreads();

  // copy out: dfr, anchors, dcnt, bandT/S
  {
    unsigned int* dst = (unsigned int*)(w + DFR_OFF);
    const unsigned int* src = (const unsigned int*)sm.dfr;
    for (int i = tid; i < (NBANDS * DCAP * 3) / 2; i += NT) dst[i] = src[i];
  }
  {
    unsigned int* dst = (unsigned int*)(w + ANCH_OFF);
    const unsigned int* src = (const unsigned int*)sm.anchors;
    for (int i = tid; i < (NCUTS * 192) / 2; i += NT) dst[i] = src[i];
  }
  if (tid < 16) {
    ((unsigned int*)(w + DCNT_OFF))[tid] = sm.dcnt[tid];
    ((double*)(w + BT_OFF))[tid] = sm.bandT[tid];
    ((double*)(w + BS_OFF))[tid] = sm.bandS[tid];
  }
}

// ======================= Kernel C: event build + sort (P6, P7) =======================
struct SMemC {
  unsigned short rkB[NCUTS * 192];
  unsigned short anchors[NCUTS * 192];
  unsigned short dfr[NBANDS * DCAP * 3];
  unsigned int dcnt[16];
  unsigned short evR[EV_MAX];
  unsigned int evAB[EV_MAX];
  unsigned int evCount, evM;
};

__global__ __launch_bounds__(NT, 1)
void kC(unsigned char* __restrict__ ws) {
  __shared__ SMemC sm;
  const int tid = threadIdx.x;
  unsigned char* w = ws + (size_t)blockIdx.x * WS_STRIDE;

  {
    const unsigned int* src = (const unsigned int*)(w + RKB_OFF);
    unsigned int* dst = (unsigned int*)sm.rkB;
    for (int i = tid; i < (NCUTS * 192) / 2; i += NT) dst[i] = src[i];
  }
  {
    const unsigned int* src = (const unsigned int*)(w + ANCH_OFF);
    unsigned int* dst = (unsigned int*)sm.anchors;
    for (int i = tid; i < (NCUTS * 192) / 2; i += NT) dst[i] = src[i];
  }
  {
    const unsigned int* src = (const unsigned int*)(w + DFR_OFF);
    unsigned int* dst = (unsigned int*)sm.dfr;
    for (int i = tid; i < (NBANDS * DCAP * 3) / 2; i += NT) dst[i] = src[i];
  }
  if (tid < 16) sm.dcnt[tid] = ((const unsigned int*)(w + DCNT_OFF))[tid];
  __syncthreads();

  // P6a: boundary events
  for (int e = tid; e < NBE; e += NT) {
    const int cut = e / W_;
    const int col = e - cut * W_;
    const unsigned short ru = sm.rkB[cut * 192 + col];
    const unsigned short rv = sm.rkB[cut * 192 + 96 + col];
    sm.evR[e] = ru > rv ? ru : rv;
    sm.evAB[e] = ((unsigned int)sm.anchors[cut * 192 + col] << 16) | sm.anchors[cut * 192 + 96 + col];
  }
  if (tid == 0) {
    unsigned int c = NBE;
    for (int q = 0; q < NBANDS; ++q) c += sm.dcnt[q];
    sm.evCount = c;
    unsigned int M = 2048;
    while (M < c) M <<= 1;
    sm.evM = M;
  }
  __syncthreads();

  // P6b: compact deferred + pad
  {
    const int cnt = (int)sm.evCount;
    const int M = (int)sm.evM;
    for (int s = tid; s < NBANDS * DCAP; s += NT) {
      const int b2 = s / DCAP;
      const int i2 = s - b2 * DCAP;
      if ((unsigned)i2 < sm.dcnt[b2]) {
        int off = NBE;
        for (int q = 0; q < b2; ++q) off += (int)sm.dcnt[q];
        const unsigned short* e3 = &sm.dfr[(b2 * DCAP + i2) * 3];
        sm.evR[off + i2] = e3[0];
        sm.evAB[off + i2] = ((unsigned int)e3[1] << 16) | e3[2];
      }
    }
    for (int e = cnt + tid; e < M; e += NT) { sm.evR[e] = 0xFFFFu; sm.evAB[e] = 0u; }
  }
  __syncthreads();

  // P7: bitonic sort events by rank key
  {
    const int M = (int)sm.evM;
    for (int k = 2; k <= M; k <<= 1) {
      for (int j = k >> 1; j > 0; j >>= 1) {
        for (int p = tid; p < (M >> 1); p += NT) {
          const int i = ((p & ~(j - 1)) << 1) | (p & (j - 1));
          const int l = i | j;
          const unsigned short ki = sm.evR[i], kl = sm.evR[l];
          const unsigned int ai = sm.evAB[i], al = sm.evAB[l];
          const bool up = ((i & k) == 0);
          const bool sw = up ? (ki > kl) : (ki < kl);
          sm.evR[i] = sw ? kl : ki;  sm.evR[l] = sw ? ki : kl;
          sm.evAB[i] = sw ? al : ai; sm.evAB[l] = sw ? ai : al;
        }
        __syncthreads();
      }
    }
  }

  // copy out events
  {
    const int M = (int)sm.evM;
    unsigned int* dstR = (unsigned int*)(w + EVR_OFF);
    const unsigned int* srcR = (const unsigned int*)sm.evR;
    for (int i = tid; i < M / 2; i += NT) dstR[i] = srcR[i];
    unsigned int* dstA = (unsigned int*)(w + EVAB_OFF);
    for (int i = tid; i < M; i += NT) dstA[i] = sm.evAB[i];
    if (tid == 0) {
      ((unsigned int*)(w + EVC_OFF))[0] = sm.evCount;
      ((unsigned int*)(w + EVC_OFF))[1] = sm.evM;
    }
  }
}

// ======================= Kernel D: serial replay (P8) =======================
struct SMemD {
  unsigned int   K[NV];
  unsigned short parG[NV];
  unsigned short evR[EV_MAX];
  unsigned int   evAB[EV_MAX];
};

__global__ __launch_bounds__(NT, 1)
void kD(unsigned char* __restrict__ ws, float* __restrict__ out) {
  __shared__ SMemD sm;
  const int tid = threadIdx.x;
  unsigned char* w = ws + (size_t)blockIdx.x * WS_STRIDE;

  const unsigned int cnt = ((const unsigned int*)(w + EVC_OFF))[0];
  const unsigned int M   = ((const unsigned int*)(w + EVC_OFF))[1];
  {
    const unsigned int* src = (const unsigned int*)(w + K_OFF);
    for (int i = tid; i < NV; i += NT) sm.K[i] = src[i];
  }
  for (int i = tid; i < NV; i += NT) sm.parG[i] = (unsigned short)0x8000u;
  {
    const unsigned int* srcR = (const unsigned int*)(w + EVR_OFF);
    unsigned int* dstR = (unsigned int*)sm.evR;
    for (int i = tid; i < (int)M / 2; i += NT) dstR[i] = srcR[i];
    const unsigned int* srcA = (const unsigned int*)(w + EVAB_OFF);
    for (int i = tid; i < (int)M; i += NT) sm.evAB[i] = srcA[i];
  }
  __syncthreads();

  if (tid == 0) {
    double T = 0.0, S = 0.0;
    {
      const double* bT = (const double*)(w + BT_OFF);
      const double* bS = (const double*)(w + BS_OFF);
      for (int q = 0; q < NBANDS; ++q) { T += bT[q]; S += bS[q]; }
    }
    for (int bs = 0; bs < (int)cnt; bs += 4) {
      int A0, A1, A2, A3, B0, B1, B2, B3, W0, W1, W2, W3;
      {
        unsigned int ab;
        if (bs + 0 < (int)cnt) { ab = sm.evAB[bs + 0]; A0 = (int)(ab >> 16); B0 = (int)(ab & 0xFFFFu); W0 = (int)sm.evR[bs + 0]; }
        else { A0 = 0; B0 = 0; W0 = 0; }
        if (bs + 1 < (int)cnt) { ab = sm.evAB[bs + 1]; A1 = (int)(ab >> 16); B1 = (int)(ab & 0xFFFFu); W1 = (int)sm.evR[bs + 1]; }
        else { A1 = 0; B1 = 0; W1 = 0; }
        if (bs + 2 < (int)cnt) { ab = sm.evAB[bs + 2]; A2 = (int)(ab >> 16); B2 = (int)(ab & 0xFFFFu); W2 = (int)sm.evR[bs + 2]; }
        else { A2 = 0; B2 = 0; W2 = 0; }
        if (bs + 3 < (int)cnt) { ab = sm.evAB[bs + 3]; A3 = (int)(ab >> 16); B3 = (int)(ab & 0xFFFFu); W3 = (int)sm.evR[bs + 3]; }
        else { A3 = 0; B3 = 0; W3 = 0; }
      }
      const float D0 = keyToFloat(sm.K[W0]);
      const float D1 = keyToFloat(sm.K[W1]);
      const float D2 = keyToFloat(sm.K[W2]);
      const float D3 = keyToFloat(sm.K[W3]);
      int fa0 = A0, fa1 = A1, fa2 = A2, fa3 = A3;
      int fb0 = B0, fb1 = B1, fb2 = B2, fb3 = B3;
      for (;;) {
        const unsigned int ea0 = sm.parG[fa0], ea1 = sm.parG[fa1];
        const unsigned int ea2 = sm.parG[fa2], ea3 = sm.parG[fa3];
        const unsigned int eb0 = sm.parG[fb0], eb1 = sm.parG[fb1];
        const unsigned int eb2 = sm.parG[fb2], eb3 = sm.parG[fb3];
        if ((ea0 & ea1 & ea2 & ea3 & eb0 & eb1 & eb2 & eb3) & 0x8000u) break;
        fa0 = (ea0 & 0x8000u) ? fa0 : (int)ea0;
        fa1 = (ea1 & 0x8000u) ? fa1 : (int)ea1;
        fa2 = (ea2 & 0x8000u) ? fa2 : (int)ea2;
        fa3 = (ea3 & 0x8000u) ? fa3 : (int)ea3;
        fb0 = (eb0 & 0x8000u) ? fb0 : (int)eb0;
        fb1 = (eb1 & 0x8000u) ? fb1 : (int)eb1;
        fb2 = (eb2 & 0x8000u) ? fb2 : (int)eb2;
        fb3 = (eb3 & 0x8000u) ? fb3 : (int)eb3;
      }
      const float ka0 = keyToFloat(sm.K[fa0]), kb0 = keyToFloat(sm.K[fb0]);
      const float ka1 = keyToFloat(sm.K[fa1]), kb1 = keyToFloat(sm.K[fb1]);
      const float ka2 = keyToFloat(sm.K[fa2]), kb2 = keyToFloat(sm.K[fb2]);
      const float ka3 = keyToFloat(sm.K[fa3]), kb3 = keyToFloat(sm.K[fb3]);
      int hy0 = -1, hy1 = -1, hy2 = -1, he0 = 0, he1 = 0, he2 = 0, nh = 0;
      #define COMMIT(Aj, Bj, faj, fbj, kaj, kbj, Dj, OKj)                        \
      {                                                                          \
        int fa = faj, fb = fbj;                                                  \
        if (fa == hy0) fa = he0;  if (fa == hy1) fa = he1;  if (fa == hy2) fa = he2; \
        if (fb == hy0) fb = he0;  if (fb == hy1) fb = he1;  if (fb == hy2) fb = he2; \
        if (OKj && fa != fb) {                                                   \
          const int y = fa > fb ? fa : fb;                                       \
          const int el = fa + fb - y;                                            \
          const float by = (y == faj) ? kaj : ((y == fbj) ? kbj                  \
                             : keyToFloat(sm.K[y]));                             \
          const float pers = Dj - by;                                            \
          if (pers > 0.0f) { T += (double)pers;                                  \
                             S += (double)(pers * logf(pers)); }                 \
          sm.parG[y] = (unsigned short)el;                                       \
          if (nh == 0) { hy0 = y; he0 = el; }                                    \
          else if (nh == 1) { hy1 = y; he1 = el; }                               \
          else if (nh == 2) { hy2 = y; he2 = el; }                               \
          ++nh;                                                                  \
          if (Aj != el && Aj != y) sm.parG[Aj] = (unsigned short)el;             \
          if (Bj != el && Bj != y) sm.parG[Bj] = (unsigned short)el;             \
        } else {                                                                 \
          if (Aj != fa) sm.parG[Aj] = (unsigned short)fa;                        \
          if (Bj != fb) sm.parG[Bj] = (unsigned short)fb;                        \
        }                                                                        \
      }
      COMMIT(A0, B0, fa0, fb0, ka0, kb0, D0, (bs + 0 < (int)cnt))
      COMMIT(A1, B1, fa1, fb1, ka1, kb1, D1, (bs + 1 < (int)cnt))
      COMMIT(A2, B2, fa2, fb2, ka2, kb2, D2, (bs + 2 < (int)cnt))
      COMMIT(A3, B3, fa3, fb3, ka3, kb3, D3, (bs + 3 < (int)cnt))
      #undef COMMIT
    }
    out[blockIdx.x] = (T > 0.0) ? (float)(log(T) - S / T) : 0.0f;
  }
}

// ======================= Monolithic fallback (R10 kernel) =======================
struct SMemM {
  unsigned int   K[SORT_N];
  unsigned short P[SORT_N];
  unsigned short parL[NV];
  unsigned short BL[NV];
  unsigned short rkB[NCUTS * 192];
  double bandT[NBANDS], bandS[NBANDS];
  unsigned int dcnt[NBANDS];
  unsigned int evCount, evM;
};

__global__ __launch_bounds__(NT, 1)
void topo_mono(const float* __restrict__ x, float* __restrict__ out) {
  __shared__ SMemM sm;
  const int tid = threadIdx.x;
  const float* img = x + (size_t)blockIdx.x * NV;

  unsigned short* dfr     = (unsigned short*)&sm.K[NV];
  unsigned short* anchors = &sm.P[NV];
  unsigned short* evR     = sm.BL;
  unsigned int*   evAB    = (unsigned int*)sm.P;

  for (int i = tid; i < SORT_N; i += NT) {
    if (i < NV) {
      unsigned int b = __float_as_uint(img[i]);
      sm.K[i] = b ^ ((b & 0x80000000u) ? 0xFFFFFFFFu : 0x80000000u);
      sm.P[i] = (unsigned short)i;
    } else { sm.K[i] = 0xFFFFFFFFu; sm.P[i] = 0xFFFFu; }
  }
  if (tid < NBANDS) { sm.dcnt[tid] = 0u; sm.bandT[tid] = 0.0; sm.bandS[tid] = 0.0; }
  __syncthreads();
  for (int k = 2; k <= SORT_N; k <<= 1) {
    for (int j = k >> 1; j > 0; j >>= 1) {
      #pragma unroll 4
      for (int p = tid; p < (SORT_N / 2); p += NT) {
        int i = ((p & ~(j - 1)) << 1) | (p & (j - 1));
        int l = i | j;
        unsigned int ki = sm.K[i], kl = sm.K[l];
        unsigned short pi = sm.P[i], pl = sm.P[l];
        bool up = ((i & k) == 0);
        bool sw = up ? (ki > kl) : (ki < kl);
        sm.K[i] = sw ? kl : ki;  sm.K[l] = sw ? ki : kl;
        sm.P[i] = sw ? pl : pi;  sm.P[l] = sw ? pi : pl;
      }
      __syncthreads();
    }
  }
  for (int t = tid; t < NV; t += NT) {
    const int vid = (int)sm.P[t];
    sm.parL[vid] = (unsigned short)(0x8000u | (unsigned int)t);
    const int r = vid / W_;
    const int c = vid - r * W_;
    if ((r % BROWS) == BROWS - 1 && r < H_ - 1) sm.rkB[(r / BROWS) * 192 + c] = (unsigned short)t;
    if ((r % BROWS) == 0 && r > 0)              sm.rkB[(r / BROWS - 1) * 192 + 96 + c] = (unsigned short)t;
  }
  {
    const int wv = tid >> 6, lane = tid & 63;
    int cnt = 0;
    for (int t0 = 0; t0 < NV; t0 += 64) {
      const int t = t0 + lane;
      const int vid = (int)sm.P[t];
      const bool mine = (vid / BVERTS) == wv;
      const unsigned long long m = __ballot(mine);
      if (mine)
        sm.BL[wv * BVERTS + cnt + __popcll(m & ((1ull << lane) - 1ull))] = (unsigned short)t;
      cnt += (int)__popcll(m);
    }
  }
  __syncthreads();
  if ((tid & 63) == 0) {
    const int b = tid >> 6;
    const int base = b * BVERTS;
    const int rtop = b * BROWS, rbot = rtop + BROWS - 1;
    unsigned short* db = &dfr[b * DCAP * 3];
    double T = 0.0, S = 0.0;
    int dc = 0;
    int t_n = (int)sm.BL[base];
    for (int j = 0; j < BVERTS; ++j) {
      const int t = t_n;
      if (j + 1 < BVERTS) t_n = (int)sm.BL[base + j + 1];
      const int vid = (int)sm.P[t];
      const float vt = keyToFloat(sm.K[t]);
      const int r = vid / W_;
      const int c = vid - r * W_;
      int n0 = (c > 0)      ? vid - 1  : vid;
      int n1 = (c < W_ - 1) ? vid + 1  : vid;
      int n2 = (r > rtop)   ? vid - W_ : vid;
      int n3 = (r < rbot)   ? vid + W_ : vid;
      int x0 = n0, x1 = n1, x2 = n2, x3 = n3;
      unsigned int p0 = sm.parL[x0], p1 = sm.parL[x1], p2 = sm.parL[x2], p3 = sm.parL[x3];
      const unsigned int self = 0x8000u | (unsigned int)t;
      if ((p0 & 0x8000u) && (int)(p0 & 0x3FFFu) > t) { x0 = vid; n0 = vid; p0 = self; }
      if ((p1 & 0x8000u) && (int)(p1 & 0x3FFFu) > t) { x1 = vid; n1 = vid; p1 = self; }
      if ((p2 & 0x8000u) && (int)(p2 & 0x3FFFu) > t) { x2 = vid; n2 = vid; p2 = self; }
      if ((p3 & 0x8000u) && (int)(p3 & 0x3FFFu) > t) { x3 = vid; n3 = vid; p3 = self; }
      while (!((p0 & p1 & p2 & p3) & 0x8000u)) {
        x0 = (p0 & 0x8000u) ? x0 : (int)p0;
        x1 = (p1 & 0x8000u) ? x1 : (int)p1;
        x2 = (p2 & 0x8000u) ? x2 : (int)p2;
        x3 = (p3 & 0x8000u) ? x3 : (int)p3;
        p0 = sm.parL[x0]; p1 = sm.parL[x1]; p2 = sm.parL[x2]; p3 = sm.parL[x3];
      }
      const float v0 = keyToFloat(sm.K[(int)(p0 & 0x3FFFu)]);
      const float v1 = keyToFloat(sm.K[(int)(p1 & 0x3FFFu)]);
      const float v2 = keyToFloat(sm.K[(int)(p2 & 0x3FFFu)]);
      const float v3 = keyToFloat(sm.K[(int)(p3 & 0x3FFFu)]);
      int mv = vid, mr = t;
      float mval = vt;
      unsigned int mtaint = ((r == rtop && b > 0) || (r == rbot && b < NBANDS - 1)) ? 1u : 0u;
      int g0 = -1, g1 = -1, g2 = -1;
      #define DO_CHAIN(pc, xc, vc)                                              \
      {                                                                         \
        const int rr = (int)(pc & 0x3FFFu);                                     \
        const unsigned int rt = (pc >> 14) & 1u;                                \
        const int rv = xc;                                                      \
        if (rr <= t && rv != mv && rv != g0 && rv != g1 && rv != g2) {          \
          int yR, yV; unsigned int yT; float ybv;                               \
          if (rr > mr) { yR = rr; yV = rv; yT = rt; ybv = vc; }                 \
          else { yR = mr; yV = mv; yT = mtaint; ybv = mval;                     \
                 mv = rv; mr = rr; mval = vc; }                                 \
          mtaint |= rt;                                                         \
          if (yT) {                                                             \
            db[dc * 3 + 0] = (unsigned short)t;                                 \
            db[dc * 3 + 1] = (unsigned short)yR;                                \
            db[dc * 3 + 2] = (unsigned short)mr;                                \
            ++dc;                                                               \
          } else {                                                              \
            const float pers = vt - ybv;                                        \
            if (pers > 0.0f) { T += (double)pers;                               \
                               S += (double)(pers * logf(pers)); }              \
          }                                                                     \
          sm.parL[yV] = (unsigned short)mv;                                     \
          g2 = g1; g1 = g0; g0 = yV;                                            \
        }                                                                       \
      }
      DO_CHAIN(p0, x0, v0)
      DO_CHAIN(p1, x1, v1)
      DO_CHAIN(p2, x2, v2)
      DO_CHAIN(p3, x3, v3)
      #undef DO_CHAIN
      sm.parL[mv] = (unsigned short)(0x8000u | (mtaint << 14) | (unsigned int)mr);
      if (vid != mv) sm.parL[vid] = (unsigned short)mv;
      if ((int)(p0 & 0x3FFFu) <= t) { if (n0 != mv) sm.parL[n0] = (unsigned short)mv;
                                      if (x0 != mv && x0 != n0) sm.parL[x0] = (unsigned short)mv; }
      if ((int)(p1 & 0x3FFFu) <= t) { if (n1 != mv) sm.parL[n1] = (unsigned short)mv;
                                      if (x1 != mv && x1 != n1) sm.parL[x1] = (unsigned short)mv; }
      if ((int)(p2 & 0x3FFFu) <= t) { if (n2 != mv) sm.parL[n2] = (unsigned short)mv;
                                      if (x2 != mv && x2 != n2) sm.parL[x2] = (unsigned short)mv; }
      if ((int)(p3 & 0x3FFFu) <= t) { if (n3 != mv) sm.parL[n3] = (unsigned short)mv;
                                      if (x3 != mv && x3 != n3) sm.parL[x3] = (unsigned short)mv; }
      if (r == rbot && b < NBANDS - 1) anchors[b * 192 + c] = (unsigned short)mr;
      if (r == rtop && b > 0)          anchors[(b - 1) * 192 + 96 + c] = (unsigned short)mr;
    }
    sm.bandT[b] = T; sm.bandS[b] = S; sm.dcnt[b] = (unsigned int)dc;
  }
  __syncthreads();
  for (int e = tid; e < NBE; e += NT) {
    const int cut = e / W_;
    const int col = e - cut * W_;
    const unsigned short ru = sm.rkB[cut * 192 + col];
    const unsigned short rv = sm.rkB[cut * 192 + 96 + col];
    evR[e] = ru > rv ? ru : rv;
    evAB[e] = ((unsigned int)anchors[cut * 192 + col] << 16) | anchors[cut * 192 + 96 + col];
  }
  for (int r2 = tid; r2 < NV; r2 += NT) sm.parL[r2] = (unsigned short)0x8000u;
  if (tid == 0) {
    unsigned int c = NBE;
    for (int q = 0; q < NBANDS; ++q) c += sm.dcnt[q];
    sm.evCount = c;
    unsigned int M = 2048;
    while (M < c) M <<= 1;
    sm.evM = M;
  }
  __syncthreads();
  {
    const int cnt = (int)sm.evCount;
    const int M = (int)sm.evM;
    for (int s = tid; s < NBANDS * DCAP; s += NT) {
      const int b2 = s / DCAP;
      const int i2 = s - b2 * DCAP;
      if ((unsigned)i2 < sm.dcnt[b2]) {
        int off = NBE;
        for (int q = 0; q < b2; ++q) off += (int)sm.dcnt[q];
        const unsigned short* e3 = &dfr[(b2 * DCAP + i2) * 3];
        evR[off + i2] = e3[0];
        evAB[off + i2] = ((unsigned int)e3[1] << 16) | e3[2];
      }
    }
    for (int e = cnt + tid; e < M; e += NT) evR[e] = 0xFFFFu;
  }
  __syncthreads();
  {
    const int M = (int)sm.evM;
    for (int k = 2; k <= M; k <<= 1) {
      for (int j = k >> 1; j > 0; j >>= 1) {
        for (int p = tid; p < (M >> 1); p += NT) {
          const int i = ((p & ~(j - 1)) << 1) | (p & (j - 1));
          const int l = i | j;
          const unsigned short ki = evR[i], kl = evR[l];
          const unsigned int ai = evAB[i], al = evAB[l];
          const bool up = ((i & k) == 0);
          const bool sw = up ? (ki > kl) : (ki < kl);
          evR[i] = sw ? kl : ki;  evR[l] = sw ? ki : kl;
          evAB[i] = sw ? al : ai; evAB[l] = sw ? ai : al;
        }
        __syncthreads();
      }
    }
  }
  if (tid == 0) {
    double T = 0.0, S = 0.0;
    for (int q = 0; q < NBANDS; ++q) { T += sm.bandT[q]; S += sm.bandS[q]; }
    const int cnt = (int)sm.evCount;
    unsigned short wn = evR[0];
    unsigned int abn = evAB[0];
    float dvn = keyToFloat(sm.K[wn]);
    for (int i = 0; i < cnt; ++i) {
      const unsigned int ab = abn;
      const float dv = dvn;
      if (i + 1 < cnt) { wn = evR[i + 1]; abn = evAB[i + 1]; dvn = keyToFloat(sm.K[wn]); }
      const int a = (int)(ab >> 16), b2 = (int)(ab & 0xFFFFu);
      int fa = a, fb = b2;
      unsigned int ea = sm.parL[fa], eb = sm.parL[fb];
      while (!((ea & eb) & 0x8000u)) {
        fa = (ea & 0x8000u) ? fa : (int)ea;
        fb = (eb & 0x8000u) ? fb : (int)eb;
        ea = sm.parL[fa]; eb = sm.parL[fb];
      }
      if (fa != fb) {
        const int y = fa > fb ? fa : fb;
        const int el = fa + fb - y;
        const float pers = dv - keyToFloat(sm.K[y]);
        if (pers > 0.0f) { T += (double)pers; S += (double)(pers * logf(pers)); }
        sm.parL[y] = (unsigned short)el;
        if (a != el && a != y)   sm.parL[a]  = (unsigned short)el;
        if (b2 != el && b2 != y) sm.parL[b2] = (unsigned short)el;
      } else {
        if (a != fa)  sm.parL[a]  = (unsigned short)fa;
        if (b2 != fb) sm.parL[b2] = (unsigned short)fb;
      }
    }
    out[blockIdx.x] = (T > 0.0) ? (float)(log(T) - S / T) : 0.0f;
  }
}

extern "C" void kernel_launch(void* const* d_in, const int* in_sizes, int n_in,
                              void* d_out, int out_size, void* d_ws, size_t ws_size,
                              hipStream_t stream) {
  (void)n_in; (void)out_size;
  const float* x = (const float*)d_in[0];
  float* out = (float*)d_out;
  int n_img = in_sizes[0] / NV;   // 64
  if (n_img <= 0) n_img = 1;
  if (ws_size >= (size_t)n_img * WS_STRIDE) {
    unsigned char* ws = (unsigned char*)d_ws;
    kA<<<n_img, NT, 0, stream>>>(x, ws);
    kB<<<n_img, NT, 0, stream>>>(ws);
    kC<<<n_img, NT, 0, stream>>>(ws);
    kD<<<n_img, NT, 0, stream>>>(ws, out);
  } else {
    topo_mono<<<n_img, NT, 0, stream>>>(x, out);
  }
}

// Round 12
// 2835.008 us; speedup vs baseline: 1.0350x; 1.0350x over previous
//
#include <hip/hip_runtime.h>

#define H_ 96
#define W_ 96
#define NV (H_ * W_)              // 9216
#define SORT_N 16384
#define NT 1024
#define NBANDS 16
#define BROWS (H_ / NBANDS)       // 6
#define BVERTS (BROWS * W_)       // 576
#define DCAP 288
#define NCUTS (NBANDS - 1)        // 15
#define NBE (NCUTS * W_)          // 1440
#define EV_MAX 8192

// ---- workspace layout (per image, stride 192 KiB) ----
#define WS_STRIDE (192 * 1024)
#define K_OFF     0
#define P_OFF     36864
#define PARL_OFF  55296
#define BL_OFF    73728
#define RKB_OFF   92160
#define DFR_OFF   98304
#define ANCH_OFF  125952
#define DCNT_OFF  131712
#define BT_OFF    131776
#define BS_OFF    131904
#define EVR_OFF   132096
#define EVAB_OFF  148480
#define EVC_OFF   181248

__device__ __forceinline__ float keyToFloat(unsigned int k) {
  return __uint_as_float((k & 0x80000000u) ? (k ^ 0x80000000u) : ~k);
}

// ======================= Kernel A: load + sort + init =======================
struct SMemA {
  unsigned int   K[SORT_N];
  unsigned short P[SORT_N];
  unsigned short parL[NV];
  unsigned short BL[NV];
  unsigned short rkB[NCUTS * 192];
};

__global__ __launch_bounds__(NT, 1)
void kA(const float* __restrict__ x, unsigned char* __restrict__ ws) {
  __shared__ SMemA sm;
  const int tid = threadIdx.x;
  const float* img = x + (size_t)blockIdx.x * NV;
  unsigned char* w = ws + (size_t)blockIdx.x * WS_STRIDE;

  for (int i = tid; i < SORT_N; i += NT) {
    if (i < NV) {
      unsigned int b = __float_as_uint(img[i]);
      sm.K[i] = b ^ ((b & 0x80000000u) ? 0xFFFFFFFFu : 0x80000000u);
      sm.P[i] = (unsigned short)i;
    } else { sm.K[i] = 0xFFFFFFFFu; sm.P[i] = 0xFFFFu; }
  }
  __syncthreads();

  for (int k = 2; k <= SORT_N; k <<= 1) {
    for (int j = k >> 1; j > 0; j >>= 1) {
      #pragma unroll 4
      for (int p = tid; p < (SORT_N / 2); p += NT) {
        int i = ((p & ~(j - 1)) << 1) | (p & (j - 1));
        int l = i | j;
        unsigned int ki = sm.K[i], kl = sm.K[l];
        unsigned short pi = sm.P[i], pl = sm.P[l];
        bool up = ((i & k) == 0);
        bool sw = up ? (ki > kl) : (ki < kl);
        sm.K[i] = sw ? kl : ki;  sm.K[l] = sw ? ki : kl;
        sm.P[i] = sw ? pl : pi;  sm.P[l] = sw ? pi : pl;
      }
      __syncthreads();
    }
  }

  for (int t = tid; t < NV; t += NT) {
    const int vid = (int)sm.P[t];
    sm.parL[vid] = (unsigned short)(0x8000u | (unsigned int)t);
    const int r = vid / W_;
    const int c = vid - r * W_;
    if ((r % BROWS) == BROWS - 1 && r < H_ - 1) sm.rkB[(r / BROWS) * 192 + c] = (unsigned short)t;
    if ((r % BROWS) == 0 && r > 0)              sm.rkB[(r / BROWS - 1) * 192 + 96 + c] = (unsigned short)t;
  }
  {
    const int wv = tid >> 6, lane = tid & 63;
    int cnt = 0;
    for (int t0 = 0; t0 < NV; t0 += 64) {
      const int t = t0 + lane;
      const int vid = (int)sm.P[t];
      const bool mine = (vid / BVERTS) == wv;
      const unsigned long long m = __ballot(mine);
      if (mine)
        sm.BL[wv * BVERTS + cnt + __popcll(m & ((1ull << lane) - 1ull))] = (unsigned short)t;
      cnt += (int)__popcll(m);
    }
  }
  __syncthreads();

  unsigned int* wK = (unsigned int*)(w + K_OFF);
  for (int i = tid; i < NV; i += NT) wK[i] = sm.K[i];
  {
    unsigned int* dst = (unsigned int*)(w + P_OFF);
    const unsigned int* src = (const unsigned int*)sm.P;
    for (int i = tid; i < NV / 2; i += NT) dst[i] = src[i];
  }
  {
    unsigned int* dst = (unsigned int*)(w + PARL_OFF);
    const unsigned int* src = (const unsigned int*)sm.parL;
    for (int i = tid; i < NV / 2; i += NT) dst[i] = src[i];
  }
  {
    unsigned int* dst = (unsigned int*)(w + BL_OFF);
    const unsigned int* src = (const unsigned int*)sm.BL;
    for (int i = tid; i < NV / 2; i += NT) dst[i] = src[i];
  }
  {
    unsigned int* dst = (unsigned int*)(w + RKB_OFF);
    const unsigned int* src = (const unsigned int*)sm.rkB;
    for (int i = tid; i < (NCUTS * 192) / 2; i += NT) dst[i] = src[i];
  }
}

// ======================= Kernel B: 16-band parallel Kruskal =======================
struct SMemB {
  double bandT[16], bandS[16];
  unsigned int   K[NV];
  unsigned short P[NV];
  unsigned short parL[NV];
  unsigned short BL[NV];
  unsigned short dfr[NBANDS * DCAP * 3];
  unsigned short anchors[NCUTS * 192];
  unsigned int dcnt[16];
};

__global__ __launch_bounds__(NT, 1)
void kB(unsigned char* __restrict__ ws) {
  __shared__ SMemB sm;
  const int tid = threadIdx.x;
  unsigned char* w = ws + (size_t)blockIdx.x * WS_STRIDE;

  {
    const unsigned int* src = (const unsigned int*)(w + K_OFF);
    for (int i = tid; i < NV; i += NT) sm.K[i] = src[i];
  }
  {
    const unsigned int* src = (const unsigned int*)(w + P_OFF);
    unsigned int* dst = (unsigned int*)sm.P;
    for (int i = tid; i < NV / 2; i += NT) dst[i] = src[i];
  }
  {
    const unsigned int* src = (const unsigned int*)(w + PARL_OFF);
    unsigned int* dst = (unsigned int*)sm.parL;
    for (int i = tid; i < NV / 2; i += NT) dst[i] = src[i];
  }
  {
    const unsigned int* src = (const unsigned int*)(w + BL_OFF);
    unsigned int* dst = (unsigned int*)sm.BL;
    for (int i = tid; i < NV / 2; i += NT) dst[i] = src[i];
  }
  if (tid < 16) { sm.dcnt[tid] = 0u; sm.bandT[tid] = 0.0; sm.bandS[tid] = 0.0; }
  __syncthreads();

  if ((tid & 63) == 0) {
    const int b = tid >> 6;
    const int base = b * BVERTS;
    const int rtop = b * BROWS, rbot = rtop + BROWS - 1;
    unsigned short* db = &sm.dfr[b * DCAP * 3];
    double T = 0.0, S = 0.0;
    int dc = 0;
    int t_n = (int)sm.BL[base];
    for (int j = 0; j < BVERTS; ++j) {
      const int t = t_n;
      if (j + 1 < BVERTS) t_n = (int)sm.BL[base + j + 1];
      const int vid = (int)sm.P[t];
      const float vt = keyToFloat(sm.K[t]);
      const int r = vid / W_;
      const int c = vid - r * W_;
      int n0 = (c > 0)      ? vid - 1  : vid;
      int n1 = (c < W_ - 1) ? vid + 1  : vid;
      int n2 = (r > rtop)   ? vid - W_ : vid;
      int n3 = (r < rbot)   ? vid + W_ : vid;
      int x0 = n0, x1 = n1, x2 = n2, x3 = n3;
      unsigned int p0 = sm.parL[x0], p1 = sm.parL[x1], p2 = sm.parL[x2], p3 = sm.parL[x3];
      const unsigned int self = 0x8000u | (unsigned int)t;
      if ((p0 & 0x8000u) && (int)(p0 & 0x3FFFu) > t) { x0 = vid; n0 = vid; p0 = self; }
      if ((p1 & 0x8000u) && (int)(p1 & 0x3FFFu) > t) { x1 = vid; n1 = vid; p1 = self; }
      if ((p2 & 0x8000u) && (int)(p2 & 0x3FFFu) > t) { x2 = vid; n2 = vid; p2 = self; }
      if ((p3 & 0x8000u) && (int)(p3 & 0x3FFFu) > t) { x3 = vid; n3 = vid; p3 = self; }
      while (!((p0 & p1 & p2 & p3) & 0x8000u)) {
        x0 = (p0 & 0x8000u) ? x0 : (int)p0;
        x1 = (p1 & 0x8000u) ? x1 : (int)p1;
        x2 = (p2 & 0x8000u) ? x2 : (int)p2;
        x3 = (p3 & 0x8000u) ? x3 : (int)p3;
        p0 = sm.parL[x0]; p1 = sm.parL[x1]; p2 = sm.parL[x2]; p3 = sm.parL[x3];
      }
      const float v0 = keyToFloat(sm.K[(int)(p0 & 0x3FFFu)]);
      const float v1 = keyToFloat(sm.K[(int)(p1 & 0x3FFFu)]);
      const float v2 = keyToFloat(sm.K[(int)(p2 & 0x3FFFu)]);
      const float v3 = keyToFloat(sm.K[(int)(p3 & 0x3FFFu)]);
      int mv = vid, mr = t;
      float mval = vt;
      unsigned int mtaint = ((r == rtop && b > 0) || (r == rbot && b < NBANDS - 1)) ? 1u : 0u;
      int g0 = -1, g1 = -1, g2 = -1;
      #define DO_CHAIN(pc, xc, vc)                                              \
      {                                                                         \
        const int rr = (int)(pc & 0x3FFFu);                                     \
        const unsigned int rt = (pc >> 14) & 1u;                                \
        const int rv = xc;                                                      \
        if (rr <= t && rv != mv && rv != g0 && rv != g1 && rv != g2) {          \
          int yR, yV; unsigned int yT; float ybv;                               \
          if (rr > mr) { yR = rr; yV = rv; yT = rt; ybv = vc; }                 \
          else { yR = mr; yV = mv; yT = mtaint; ybv = mval;                     \
                 mv = rv; mr = rr; mval = vc; }                                 \
          mtaint |= rt;                                                         \
          if (yT) {                                                             \
            db[dc * 3 + 0] = (unsigned short)t;                                 \
            db[dc * 3 + 1] = (unsigned short)yR;                                \
            db[dc * 3 + 2] = (unsigned short)mr;                                \
            ++dc;                                                               \
          } else {                                                              \
            const float pers = vt - ybv;                                        \
            if (pers > 0.0f) { T += (double)pers;                               \
                               S += (double)(pers * logf(pers)); }              \
          }                                                                     \
          sm.parL[yV] = (unsigned short)mv;                                     \
          g2 = g1; g1 = g0; g0 = yV;                                            \
        }                                                                       \
      }
      DO_CHAIN(p0, x0, v0)
      DO_CHAIN(p1, x1, v1)
      DO_CHAIN(p2, x2, v2)
      DO_CHAIN(p3, x3, v3)
      #undef DO_CHAIN
      sm.parL[mv] = (unsigned short)(0x8000u | (mtaint << 14) | (unsigned int)mr);
      if (vid != mv) sm.parL[vid] = (unsigned short)mv;
      if ((int)(p0 & 0x3FFFu) <= t) { if (n0 != mv) sm.parL[n0] = (unsigned short)mv;
                                      if (x0 != mv && x0 != n0) sm.parL[x0] = (unsigned short)mv; }
      if ((int)(p1 & 0x3FFFu) <= t) { if (n1 != mv) sm.parL[n1] = (unsigned short)mv;
                                      if (x1 != mv && x1 != n1) sm.parL[x1] = (unsigned short)mv; }
      if ((int)(p2 & 0x3FFFu) <= t) { if (n2 != mv) sm.parL[n2] = (unsigned short)mv;
                                      if (x2 != mv && x2 != n2) sm.parL[x2] = (unsigned short)mv; }
      if ((int)(p3 & 0x3FFFu) <= t) { if (n3 != mv) sm.parL[n3] = (unsigned short)mv;
                                      if (x3 != mv && x3 != n3) sm.parL[x3] = (unsigned short)mv; }
      if (r == rbot && b < NBANDS - 1) sm.anchors[b * 192 + c] = (unsigned short)mr;
      if (r == rtop && b > 0)          sm.anchors[(b - 1) * 192 + 96 + c] = (unsigned short)mr;
    }
    sm.bandT[b] = T; sm.bandS[b] = S; sm.dcnt[b] = (unsigned int)dc;
  }
  __syncthreads();

  {
    unsigned int* dst = (unsigned int*)(w + DFR_OFF);
    const unsigned int* src = (const unsigned int*)sm.dfr;
    for (int i = tid; i < (NBANDS * DCAP * 3) / 2; i += NT) dst[i] = src[i];
  }
  {
    unsigned int* dst = (unsigned int*)(w + ANCH_OFF);
    const unsigned int* src = (const unsigned int*)sm.anchors;
    for (int i = tid; i < (NCUTS * 192) / 2; i += NT) dst[i] = src[i];
  }
  if (tid < 16) {
    ((unsigned int*)(w + DCNT_OFF))[tid] = sm.dcnt[tid];
    ((double*)(w + BT_OFF))[tid] = sm.bandT[tid];
    ((double*)(w + BS_OFF))[tid] = sm.bandS[tid];
  }
}

// ======================= Kernel C: event build + sort =======================
struct SMemC {
  unsigned short rkB[NCUTS * 192];
  unsigned short anchors[NCUTS * 192];
  unsigned short dfr[NBANDS * DCAP * 3];
  unsigned int dcnt[16];
  unsigned short evR[EV_MAX];
  unsigned int evAB[EV_MAX];
  unsigned int evCount, evM;
};

__global__ __launch_bounds__(NT, 1)
void kC(unsigned char* __restrict__ ws) {
  __shared__ SMemC sm;
  const int tid = threadIdx.x;
  unsigned char* w = ws + (size_t)blockIdx.x * WS_STRIDE;

  {
    const unsigned int* src = (const unsigned int*)(w + RKB_OFF);
    unsigned int* dst = (unsigned int*)sm.rkB;
    for (int i = tid; i < (NCUTS * 192) / 2; i += NT) dst[i] = src[i];
  }
  {
    const unsigned int* src = (const unsigned int*)(w + ANCH_OFF);
    unsigned int* dst = (unsigned int*)sm.anchors;
    for (int i = tid; i < (NCUTS * 192) / 2; i += NT) dst[i] = src[i];
  }
  {
    const unsigned int* src = (const unsigned int*)(w + DFR_OFF);
    unsigned int* dst = (unsigned int*)sm.dfr;
    for (int i = tid; i < (NBANDS * DCAP * 3) / 2; i += NT) dst[i] = src[i];
  }
  if (tid < 16) sm.dcnt[tid] = ((const unsigned int*)(w + DCNT_OFF))[tid];
  __syncthreads();

  for (int e = tid; e < NBE; e += NT) {
    const int cut = e / W_;
    const int col = e - cut * W_;
    const unsigned short ru = sm.rkB[cut * 192 + col];
    const unsigned short rv = sm.rkB[cut * 192 + 96 + col];
    sm.evR[e] = ru > rv ? ru : rv;
    sm.evAB[e] = ((unsigned int)sm.anchors[cut * 192 + col] << 16) | sm.anchors[cut * 192 + 96 + col];
  }
  if (tid == 0) {
    unsigned int c = NBE;
    for (int q = 0; q < NBANDS; ++q) c += sm.dcnt[q];
    sm.evCount = c;
    unsigned int M = 2048;
    while (M < c) M <<= 1;
    sm.evM = M;
  }
  __syncthreads();

  {
    const int cnt = (int)sm.evCount;
    const int M = (int)sm.evM;
    for (int s = tid; s < NBANDS * DCAP; s += NT) {
      const int b2 = s / DCAP;
      const int i2 = s - b2 * DCAP;
      if ((unsigned)i2 < sm.dcnt[b2]) {
        int off = NBE;
        for (int q = 0; q < b2; ++q) off += (int)sm.dcnt[q];
        const unsigned short* e3 = &sm.dfr[(b2 * DCAP + i2) * 3];
        sm.evR[off + i2] = e3[0];
        sm.evAB[off + i2] = ((unsigned int)e3[1] << 16) | e3[2];
      }
    }
    for (int e = cnt + tid; e < M; e += NT) { sm.evR[e] = 0xFFFFu; sm.evAB[e] = 0u; }
  }
  __syncthreads();

  {
    const int M = (int)sm.evM;
    for (int k = 2; k <= M; k <<= 1) {
      for (int j = k >> 1; j > 0; j >>= 1) {
        for (int p = tid; p < (M >> 1); p += NT) {
          const int i = ((p & ~(j - 1)) << 1) | (p & (j - 1));
          const int l = i | j;
          const unsigned short ki = sm.evR[i], kl = sm.evR[l];
          const unsigned int ai = sm.evAB[i], al = sm.evAB[l];
          const bool up = ((i & k) == 0);
          const bool sw = up ? (ki > kl) : (ki < kl);
          sm.evR[i] = sw ? kl : ki;  sm.evR[l] = sw ? ki : kl;
          sm.evAB[i] = sw ? al : ai; sm.evAB[l] = sw ? ai : al;
        }
        __syncthreads();
      }
    }
  }

  {
    const int M = (int)sm.evM;
    unsigned int* dstR = (unsigned int*)(w + EVR_OFF);
    const unsigned int* srcR = (const unsigned int*)sm.evR;
    for (int i = tid; i < M / 2; i += NT) dstR[i] = srcR[i];
    unsigned int* dstA = (unsigned int*)(w + EVAB_OFF);
    for (int i = tid; i < M; i += NT) dstA[i] = sm.evAB[i];
    if (tid == 0) {
      ((unsigned int*)(w + EVC_OFF))[0] = sm.evCount;
      ((unsigned int*)(w + EVC_OFF))[1] = sm.evM;
    }
  }
}

// ======================= Kernel D: wave-parallel chase + serial commit =======================
struct SMemD {
  unsigned int   K[NV];
  unsigned short parG[NV];
  unsigned short evR[EV_MAX];
  unsigned int   evAB[EV_MAX];
  // per-chunk scratch (wave 0 -> lane 0 handoff)
  unsigned short sa[64], sb[64], sfa[64], sfb[64];
  float ska[64], skb[64], sdv[64];
};

__global__ __launch_bounds__(NT, 1)
void kD(unsigned char* __restrict__ ws, float* __restrict__ out) {
  __shared__ SMemD sm;
  const int tid = threadIdx.x;
  unsigned char* w = ws + (size_t)blockIdx.x * WS_STRIDE;

  const unsigned int cnt = ((const unsigned int*)(w + EVC_OFF))[0];
  const unsigned int M   = ((const unsigned int*)(w + EVC_OFF))[1];
  {
    const unsigned int* src = (const unsigned int*)(w + K_OFF);
    for (int i = tid; i < NV; i += NT) sm.K[i] = src[i];
  }
  for (int i = tid; i < NV; i += NT) sm.parG[i] = (unsigned short)0x8000u;
  {
    const unsigned int* srcR = (const unsigned int*)(w + EVR_OFF);
    unsigned int* dstR = (unsigned int*)sm.evR;
    for (int i = tid; i < (int)M / 2; i += NT) dstR[i] = srcR[i];
    const unsigned int* srcA = (const unsigned int*)(w + EVAB_OFF);
    for (int i = tid; i < (int)M; i += NT) sm.evAB[i] = srcA[i];
  }
  __syncthreads();

  double T = 0.0, S = 0.0;
  if (tid == 0) {
    const double* bT = (const double*)(w + BT_OFF);
    const double* bS = (const double*)(w + BS_OFF);
    for (int q = 0; q < NBANDS; ++q) { T += bT[q]; S += bS[q]; }
  }

  // uniform chunk loop: all 1024 threads iterate the same trip count so
  // __syncthreads() is legal; wave 0 chases, lane 0 commits.
  const int nChunks = ((int)cnt + 63) / 64;
  for (int ch = 0; ch < nChunks; ++ch) {
    const int bs = ch * 64;
    if (tid < 64) {
      const int j = bs + tid;
      int a = 0, b = 0, W = 0;
      if (j < (int)cnt) {
        const unsigned int ab = sm.evAB[j];
        a = (int)(ab >> 16); b = (int)(ab & 0xFFFFu);
        W = (int)sm.evR[j];
      }
      int fa = a, fb = b;
      // parallel snapshot chase (64 events, both endpoints)
      for (;;) {
        const unsigned int ea = sm.parG[fa];
        const unsigned int eb = sm.parG[fb];
        const bool done = ((ea & eb) & 0x8000u) != 0u;
        fa = (ea & 0x8000u) ? fa : (int)ea;
        fb = (eb & 0x8000u) ? fb : (int)eb;
        if (__all(done)) break;
      }
      sm.sa[tid] = (unsigned short)a;   sm.sb[tid] = (unsigned short)b;
      sm.sfa[tid] = (unsigned short)fa; sm.sfb[tid] = (unsigned short)fb;
      sm.ska[tid] = keyToFloat(sm.K[fa]);
      sm.skb[tid] = keyToFloat(sm.K[fb]);
      sm.sdv[tid] = keyToFloat(sm.K[W]);
    }
    __syncthreads();
    if (tid == 0) {
      const int lim = ((int)cnt - bs) < 64 ? ((int)cnt - bs) : 64;
      for (int i = 0; i < lim; ++i) {
        const int a = (int)sm.sa[i], b = (int)sm.sb[i];
        const int sfa = (int)sm.sfa[i], sfb = (int)sm.sfb[i];
        int fa = sfa, fb = sfb;
        // short re-verify (snapshot roots may have been demoted this chunk)
        unsigned int ea = sm.parG[fa], eb = sm.parG[fb];
        while (!((ea & eb) & 0x8000u)) {
          fa = (ea & 0x8000u) ? fa : (int)ea;
          fb = (eb & 0x8000u) ? fb : (int)eb;
          ea = sm.parG[fa]; eb = sm.parG[fb];
        }
        if (fa != fb) {
          const int y = fa > fb ? fa : fb;
          const int el = fa + fb - y;
          const float by = (y == sfa) ? sm.ska[i]
                         : ((y == sfb) ? sm.skb[i] : keyToFloat(sm.K[y]));
          const float pers = sm.sdv[i] - by;
          if (pers > 0.0f) { T += (double)pers; S += (double)(pers * logf(pers)); }
          sm.parG[y] = (unsigned short)el;
          if (a != el && a != y)     sm.parG[a]   = (unsigned short)el;
          if (b != el && b != y)     sm.parG[b]   = (unsigned short)el;
          if (sfa != el && sfa != y) sm.parG[sfa] = (unsigned short)el;
          if (sfb != el && sfb != y) sm.parG[sfb] = (unsigned short)el;
        } else {
          if (a != fa) sm.parG[a] = (unsigned short)fa;
          if (b != fb) sm.parG[b] = (unsigned short)fb;
        }
      }
    }
    __syncthreads();
  }

  if (tid == 0)
    out[blockIdx.x] = (T > 0.0) ? (float)(log(T) - S / T) : 0.0f;
}

// ======================= Monolithic fallback (R10) =======================
struct SMemM {
  unsigned int   K[SORT_N];
  unsigned short P[SORT_N];
  unsigned short parL[NV];
  unsigned short BL[NV];
  unsigned short rkB[NCUTS * 192];
  double bandT[NBANDS], bandS[NBANDS];
  unsigned int dcnt[NBANDS];
  unsigned int evCount, evM;
};

__global__ __launch_bounds__(NT, 1)
void topo_mono(const float* __restrict__ x, float* __restrict__ out) {
  __shared__ SMemM sm;
  const int tid = threadIdx.x;
  const float* img = x + (size_t)blockIdx.x * NV;

  unsigned short* dfr     = (unsigned short*)&sm.K[NV];
  unsigned short* anchors = &sm.P[NV];
  unsigned short* evR     = sm.BL;
  unsigned int*   evAB    = (unsigned int*)sm.P;

  for (int i = tid; i < SORT_N; i += NT) {
    if (i < NV) {
      unsigned int b = __float_as_uint(img[i]);
      sm.K[i] = b ^ ((b & 0x80000000u) ? 0xFFFFFFFFu : 0x80000000u);
      sm.P[i] = (unsigned short)i;
    } else { sm.K[i] = 0xFFFFFFFFu; sm.P[i] = 0xFFFFu; }
  }
  if (tid < NBANDS) { sm.dcnt[tid] = 0u; sm.bandT[tid] = 0.0; sm.bandS[tid] = 0.0; }
  __syncthreads();
  for (int k = 2; k <= SORT_N; k <<= 1) {
    for (int j = k >> 1; j > 0; j >>= 1) {
      #pragma unroll 4
      for (int p = tid; p < (SORT_N / 2); p += NT) {
        int i = ((p & ~(j - 1)) << 1) | (p & (j - 1));
        int l = i | j;
        unsigned int ki = sm.K[i], kl = sm.K[l];
        unsigned short pi = sm.P[i], pl = sm.P[l];
        bool up = ((i & k) == 0);
        bool sw = up ? (ki > kl) : (ki < kl);
        sm.K[i] = sw ? kl : ki;  sm.K[l] = sw ? ki : kl;
        sm.P[i] = sw ? pl : pi;  sm.P[l] = sw ? pi : pl;
      }
      __syncthreads();
    }
  }
  for (int t = tid; t < NV; t += NT) {
    const int vid = (int)sm.P[t];
    sm.parL[vid] = (unsigned short)(0x8000u | (unsigned int)t);
    const int r = vid / W_;
    const int c = vid - r * W_;
    if ((r % BROWS) == BROWS - 1 && r < H_ - 1) sm.rkB[(r / BROWS) * 192 + c] = (unsigned short)t;
    if ((r % BROWS) == 0 && r > 0)              sm.rkB[(r / BROWS - 1) * 192 + 96 + c] = (unsigned short)t;
  }
  {
    const int wv = tid >> 6, lane = tid & 63;
    int cnt = 0;
    for (int t0 = 0; t0 < NV; t0 += 64) {
      const int t = t0 + lane;
      const int vid = (int)sm.P[t];
      const bool mine = (vid / BVERTS) == wv;
      const unsigned long long m = __ballot(mine);
      if (mine)
        sm.BL[wv * BVERTS + cnt + __popcll(m & ((1ull << lane) - 1ull))] = (unsigned short)t;
      cnt += (int)__popcll(m);
    }
  }
  __syncthreads();
  if ((tid & 63) == 0) {
    const int b = tid >> 6;
    const int base = b * BVERTS;
    const int rtop = b * BROWS, rbot = rtop + BROWS - 1;
    unsigned short* db = &dfr[b * DCAP * 3];
    double T = 0.0, S = 0.0;
    int dc = 0;
    int t_n = (int)sm.BL[base];
    for (int j = 0; j < BVERTS; ++j) {
      const int t = t_n;
      if (j + 1 < BVERTS) t_n = (int)sm.BL[base + j + 1];
      const int vid = (int)sm.P[t];
      const float vt = keyToFloat(sm.K[t]);
      const int r = vid / W_;
      const int c = vid - r * W_;
      int n0 = (c > 0)      ? vid - 1  : vid;
      int n1 = (c < W_ - 1) ? vid + 1  : vid;
      int n2 = (r > rtop)   ? vid - W_ : vid;
      int n3 = (r < rbot)   ? vid + W_ : vid;
      int x0 = n0, x1 = n1, x2 = n2, x3 = n3;
      unsigned int p0 = sm.parL[x0], p1 = sm.parL[x1], p2 = sm.parL[x2], p3 = sm.parL[x3];
      const unsigned int self = 0x8000u | (unsigned int)t;
      if ((p0 & 0x8000u) && (int)(p0 & 0x3FFFu) > t) { x0 = vid; n0 = vid; p0 = self; }
      if ((p1 & 0x8000u) && (int)(p1 & 0x3FFFu) > t) { x1 = vid; n1 = vid; p1 = self; }
      if ((p2 & 0x8000u) && (int)(p2 & 0x3FFFu) > t) { x2 = vid; n2 = vid; p2 = self; }
      if ((p3 & 0x8000u) && (int)(p3 & 0x3FFFu) > t) { x3 = vid; n3 = vid; p3 = self; }
      while (!((p0 & p1 & p2 & p3) & 0x8000u)) {
        x0 = (p0 & 0x8000u) ? x0 : (int)p0;
        x1 = (p1 & 0x8000u) ? x1 : (int)p1;
        x2 = (p2 & 0x8000u) ? x2 : (int)p2;
        x3 = (p3 & 0x8000u) ? x3 : (int)p3;
        p0 = sm.parL[x0]; p1 = sm.parL[x1]; p2 = sm.parL[x2]; p3 = sm.parL[x3];
      }
      const float v0 = keyToFloat(sm.K[(int)(p0 & 0x3FFFu)]);
      const float v1 = keyToFloat(sm.K[(int)(p1 & 0x3FFFu)]);
      const float v2 = keyToFloat(sm.K[(int)(p2 & 0x3FFFu)]);
      const float v3 = keyToFloat(sm.K[(int)(p3 & 0x3FFFu)]);
      int mv = vid, mr = t;
      float mval = vt;
      unsigned int mtaint = ((r == rtop && b > 0) || (r == rbot && b < NBANDS - 1)) ? 1u : 0u;
      int g0 = -1, g1 = -1, g2 = -1;
      #define DO_CHAIN(pc, xc, vc)                                              \
      {                                                                         \
        const int rr = (int)(pc & 0x3FFFu);                                     \
        const unsigned int rt = (pc >> 14) & 1u;                                \
        const int rv = xc;                                                      \
        if (rr <= t && rv != mv && rv != g0 && rv != g1 && rv != g2) {          \
          int yR, yV; unsigned int yT; float ybv;                               \
          if (rr > mr) { yR = rr; yV = rv; yT = rt; ybv = vc; }                 \
          else { yR = mr; yV = mv; yT = mtaint; ybv = mval;                     \
                 mv = rv; mr = rr; mval = vc; }                                 \
          mtaint |= rt;                                                         \
          if (yT) {                                                             \
            db[dc * 3 + 0] = (unsigned short)t;                                 \
            db[dc * 3 + 1] = (unsigned short)yR;                                \
            db[dc * 3 + 2] = (unsigned short)mr;                                \
            ++dc;                                                               \
          } else {                                                              \
            const float pers = vt - ybv;                                        \
            if (pers > 0.0f) { T += (double)pers;                               \
                               S += (double)(pers * logf(pers)); }              \
          }                                                                     \
          sm.parL[yV] = (unsigned short)mv;                                     \
          g2 = g1; g1 = g0; g0 = yV;                                            \
        }                                                                       \
      }
      DO_CHAIN(p0, x0, v0)
      DO_CHAIN(p1, x1, v1)
      DO_CHAIN(p2, x2, v2)
      DO_CHAIN(p3, x3, v3)
      #undef DO_CHAIN
      sm.parL[mv] = (unsigned short)(0x8000u | (mtaint << 14) | (unsigned int)mr);
      if (vid != mv) sm.parL[vid] = (unsigned short)mv;
      if ((int)(p0 & 0x3FFFu) <= t) { if (n0 != mv) sm.parL[n0] = (unsigned short)mv;
                                      if (x0 != mv && x0 != n0) sm.parL[x0] = (unsigned short)mv; }
      if ((int)(p1 & 0x3FFFu) <= t) { if (n1 != mv) sm.parL[n1] = (unsigned short)mv;
                                      if (x1 != mv && x1 != n1) sm.parL[x1] = (unsigned short)mv; }
      if ((int)(p2 & 0x3FFFu) <= t) { if (n2 != mv) sm.parL[n2] = (unsigned short)mv;
                                      if (x2 != mv && x2 != n2) sm.parL[x2] = (unsigned short)mv; }
      if ((int)(p3 & 0x3FFFu) <= t) { if (n3 != mv) sm.parL[n3] = (unsigned short)mv;
                                      if (x3 != mv && x3 != n3) sm.parL[x3] = (unsigned short)mv; }
      if (r == rbot && b < NBANDS - 1) anchors[b * 192 + c] = (unsigned short)mr;
      if (r == rtop && b > 0)          anchors[(b - 1) * 192 + 96 + c] = (unsigned short)mr;
    }
    sm.bandT[b] = T; sm.bandS[b] = S; sm.dcnt[b] = (unsigned int)dc;
  }
  __syncthreads();
  for (int e = tid; e < NBE; e += NT) {
    const int cut = e / W_;
    const int col = e - cut * W_;
    const unsigned short ru = sm.rkB[cut * 192 + col];
    const unsigned short rv = sm.rkB[cut * 192 + 96 + col];
    evR[e] = ru > rv ? ru : rv;
    evAB[e] = ((unsigned int)anchors[cut * 192 + col] << 16) | anchors[cut * 192 + 96 + col];
  }
  for (int r2 = tid; r2 < NV; r2 += NT) sm.parL[r2] = (unsigned short)0x8000u;
  if (tid == 0) {
    unsigned int c = NBE;
    for (int q = 0; q < NBANDS; ++q) c += sm.dcnt[q];
    sm.evCount = c;
    unsigned int M = 2048;
    while (M < c) M <<= 1;
    sm.evM = M;
  }
  __syncthreads();
  {
    const int cnt = (int)sm.evCount;
    const int M = (int)sm.evM;
    for (int s = tid; s < NBANDS * DCAP; s += NT) {
      const int b2 = s / DCAP;
      const int i2 = s - b2 * DCAP;
      if ((unsigned)i2 < sm.dcnt[b2]) {
        int off = NBE;
        for (int q = 0; q < b2; ++q) off += (int)sm.dcnt[q];
        const unsigned short* e3 = &dfr[(b2 * DCAP + i2) * 3];
        evR[off + i2] = e3[0];
        evAB[off + i2] = ((unsigned int)e3[1] << 16) | e3[2];
      }
    }
    for (int e = cnt + tid; e < M; e += NT) evR[e] = 0xFFFFu;
  }
  __syncthreads();
  {
    const int M = (int)sm.evM;
    for (int k = 2; k <= M; k <<= 1) {
      for (int j = k >> 1; j > 0; j >>= 1) {
        for (int p = tid; p < (M >> 1); p += NT) {
          const int i = ((p & ~(j - 1)) << 1) | (p & (j - 1));
          const int l = i | j;
          const unsigned short ki = evR[i], kl = evR[l];
          const unsigned int ai = evAB[i], al = evAB[l];
          const bool up = ((i & k) == 0);
          const bool sw = up ? (ki > kl) : (ki < kl);
          evR[i] = sw ? kl : ki;  evR[l] = sw ? ki : kl;
          evAB[i] = sw ? al : ai; evAB[l] = sw ? ai : al;
        }
        __syncthreads();
      }
    }
  }
  if (tid == 0) {
    double T = 0.0, S = 0.0;
    for (int q = 0; q < NBANDS; ++q) { T += sm.bandT[q]; S += sm.bandS[q]; }
    const int cnt = (int)sm.evCount;
    unsigned short wn = evR[0];
    unsigned int abn = evAB[0];
    float dvn = keyToFloat(sm.K[wn]);
    for (int i = 0; i < cnt; ++i) {
      const unsigned int ab = abn;
      const float dv = dvn;
      if (i + 1 < cnt) { wn = evR[i + 1]; abn = evAB[i + 1]; dvn = keyToFloat(sm.K[wn]); }
      const int a = (int)(ab >> 16), b2 = (int)(ab & 0xFFFFu);
      int fa = a, fb = b2;
      unsigned int ea = sm.parL[fa], eb = sm.parL[fb];
      while (!((ea & eb) & 0x8000u)) {
        fa = (ea & 0x8000u) ? fa : (int)ea;
        fb = (eb & 0x8000u) ? fb : (int)eb;
        ea = sm.parL[fa]; eb = sm.parL[fb];
      }
      if (fa != fb) {
        const int y = fa > fb ? fa : fb;
        const int el = fa + fb - y;
        const float pers = dv - keyToFloat(sm.K[y]);
        if (pers > 0.0f) { T += (double)pers; S += (double)(pers * logf(pers)); }
        sm.parL[y] = (unsigned short)el;
        if (a != el && a != y)   sm.parL[a]  = (unsigned short)el;
        if (b2 != el && b2 != y) sm.parL[b2] = (unsigned short)el;
      } else {
        if (a != fa)  sm.parL[a]  = (unsigned short)fa;
        if (b2 != fb) sm.parL[b2] = (unsigned short)fb;
      }
    }
    out[blockIdx.x] = (T > 0.0) ? (float)(log(T) - S / T) : 0.0f;
  }
}

extern "C" void kernel_launch(void* const* d_in, const int* in_sizes, int n_in,
                              void* d_out, int out_size, void* d_ws, size_t ws_size,
                              hipStream_t stream) {
  (void)n_in; (void)out_size;
  const float* x = (const float*)d_in[0];
  float* out = (float*)d_out;
  int n_img = in_sizes[0] / NV;   // 64
  if (n_img <= 0) n_img = 1;
  if (ws_size >= (size_t)n_img * WS_STRIDE) {
    unsigned char* ws = (unsigned char*)d_ws;
    kA<<<n_img, NT, 0, stream>>>(x, ws);
    kB<<<n_img, NT, 0, stream>>>(ws);
    kC<<<n_img, NT, 0, stream>>>(ws);
    kD<<<n_img, NT, 0, stream>>>(ws, out);
  } else {
    topo_mono<<<n_img, NT, 0, stream>>>(x, out);
  }
}

// Round 14
// 2526.650 us; speedup vs baseline: 1.1613x; 1.1220x over previous
//
#include <hip/hip_runtime.h>

#define H_ 96
#define W_ 96
#define NV (H_ * W_)              // 9216
#define SORT_N 16384
#define NT 1024
#define NBANDS 16
#define BROWS 6
#define BVERTS 576
#define DCAP 288                  // proven: deferred/band <= 287
#define NCUTS 15
#define CUT_N 2048

// ws per-image layout (levels 1-3 deferred events, u64 each)
#define WS_STRIDE (160 * 1024)
#define L1_OFF 0                  // 8 regions x 768
#define L2_OFF 49152              // 4 regions x 1536
#define L3_OFF 98304              // 2 regions x 3072
#define L1CAP 768
#define L2CAP 1536
#define L3CAP 3072

__device__ __forceinline__ float keyToFloat(unsigned int k) {
  return __uint_as_float((k & 0x80000000u) ? (k ^ 0x80000000u) : ~k);
}

// LDS: 64K + 32K + 18K + 18K + 18K + 5.6K + 0.4K = 159.8KB <= 160KiB
struct SMem {
  unsigned int   K[SORT_N];        // keys by rank; tail [NV..): dfr0 16x288x3 u16 (27648B)
  unsigned short P[SORT_N];        // rank->vid; tail [NV..): anchors 15x192 u16
  unsigned short parU[NV];         // band phase: vid-indexed UF; levels: rank-indexed U_l
  unsigned short rspan[NV];        // rank-indexed (minrow<<8|maxrow); persistent across levels
  unsigned short BLarena[NV];      // band lists; then cutEv (2048 x {key,pay} u32 = 16KB)
  unsigned short rkB[NCUTS * 192];
  double accT[16], accS[16];
  unsigned int dcnt0[16];
  unsigned int dcntL[3][8];
};

__global__ __launch_bounds__(NT, 1)
void topo_tree(const float* __restrict__ x, float* __restrict__ out,
               unsigned char* __restrict__ ws) {
  __shared__ SMem sm;
  const int tid = threadIdx.x;
  const float* img = x + (size_t)blockIdx.x * NV;
  unsigned char* w = ws + (size_t)blockIdx.x * WS_STRIDE;
  unsigned short* dfr0    = (unsigned short*)&sm.K[NV];
  unsigned short* anchors = &sm.P[NV];
  unsigned short* BL      = sm.BLarena;
  unsigned int*   cutEv   = (unsigned int*)sm.BLarena;

  // ---- P1: order-preserving keys ----
  for (int i = tid; i < SORT_N; i += NT) {
    if (i < NV) {
      unsigned int b = __float_as_uint(img[i]);
      sm.K[i] = b ^ ((b & 0x80000000u) ? 0xFFFFFFFFu : 0x80000000u);
      sm.P[i] = (unsigned short)i;
    } else { sm.K[i] = 0xFFFFFFFFu; sm.P[i] = 0xFFFFu; }
  }
  if (tid < 16) { sm.dcnt0[tid] = 0u; sm.accT[tid] = 0.0; sm.accS[tid] = 0.0; }
  if (tid < 24) ((unsigned int*)sm.dcntL)[tid] = 0u;
  __syncthreads();

  // ---- P2: bitonic sort (K,P) ----
  for (int k = 2; k <= SORT_N; k <<= 1) {
    for (int j = k >> 1; j > 0; j >>= 1) {
      #pragma unroll 4
      for (int p = tid; p < (SORT_N / 2); p += NT) {
        int i = ((p & ~(j - 1)) << 1) | (p & (j - 1));
        int l = i | j;
        unsigned int ki = sm.K[i], kl = sm.K[l];
        unsigned short pi = sm.P[i], pl = sm.P[l];
        bool up = ((i & k) == 0);
        bool sw = up ? (ki > kl) : (ki < kl);
        sm.K[i] = sw ? kl : ki;  sm.K[l] = sw ? ki : kl;
        sm.P[i] = sw ? pl : pi;  sm.P[l] = sw ? pi : pl;
      }
      __syncthreads();
    }
  }

  // ---- P3: scatter init: parU[vid]=root(rank), rspan[rank]=row, rkB ----
  for (int t = tid; t < NV; t += NT) {
    const int vid = (int)sm.P[t];
    sm.parU[vid] = (unsigned short)(0x8000u | (unsigned int)t);
    const int r = vid / W_;
    const int c = vid - r * W_;
    sm.rspan[t] = (unsigned short)((r << 8) | r);
    if ((r % BROWS) == BROWS - 1 && r < H_ - 1) sm.rkB[(r / BROWS) * 192 + c] = (unsigned short)t;
    if ((r % BROWS) == 0 && r > 0)              sm.rkB[(r / BROWS - 1) * 192 + 96 + c] = (unsigned short)t;
  }
  // ---- P4: band lists ----
  {
    const int wv = tid >> 6, lane = tid & 63;
    int cnt = 0;
    for (int t0 = 0; t0 < NV; t0 += 64) {
      const int t = t0 + lane;
      const int vid = (int)sm.P[t];
      const bool mine = (vid / BVERTS) == wv;
      const unsigned long long m = __ballot(mine);
      if (mine)
        BL[wv * BVERTS + cnt + __popcll(m & ((1ull << lane) - 1ull))] = (unsigned short)t;
      cnt += (int)__popcll(m);
    }
  }
  __syncthreads();

  // ---- P5: 16-band parallel Kruskal with rowspan taint ----
  if ((tid & 63) == 0) {
    const int b = tid >> 6;
    const int base = b * BVERTS;
    const int rtop = b * BROWS, rbot = rtop + BROWS - 1;
    const bool tTop = (b > 0), tBot = (b < NBANDS - 1);
    unsigned short* db = &dfr0[b * DCAP * 3];
    double T = 0.0, S = 0.0;
    int dc = 0;
    int t_n = (int)BL[base];
    for (int j = 0; j < BVERTS; ++j) {
      const int t = t_n;
      if (j + 1 < BVERTS) t_n = (int)BL[base + j + 1];
      const int vid = (int)sm.P[t];
      const float vt = keyToFloat(sm.K[t]);
      const int r = vid / W_;
      const int c = vid - r * W_;
      int n0 = (c > 0)      ? vid - 1  : vid;
      int n1 = (c < W_ - 1) ? vid + 1  : vid;
      int n2 = (r > rtop)   ? vid - W_ : vid;
      int n3 = (r < rbot)   ? vid + W_ : vid;
      int x0 = n0, x1 = n1, x2 = n2, x3 = n3;
      unsigned int p0 = sm.parU[x0], p1 = sm.parU[x1], p2 = sm.parU[x2], p3 = sm.parU[x3];
      const unsigned int self = 0x8000u | (unsigned int)t;
      if ((p0 & 0x8000u) && (int)(p0 & 0x3FFFu) > t) { x0 = vid; n0 = vid; p0 = self; }
      if ((p1 & 0x8000u) && (int)(p1 & 0x3FFFu) > t) { x1 = vid; n1 = vid; p1 = self; }
      if ((p2 & 0x8000u) && (int)(p2 & 0x3FFFu) > t) { x2 = vid; n2 = vid; p2 = self; }
      if ((p3 & 0x8000u) && (int)(p3 & 0x3FFFu) > t) { x3 = vid; n3 = vid; p3 = self; }
      while (!((p0 & p1 & p2 & p3) & 0x8000u)) {
        x0 = (p0 & 0x8000u) ? x0 : (int)p0;
        x1 = (p1 & 0x8000u) ? x1 : (int)p1;
        x2 = (p2 & 0x8000u) ? x2 : (int)p2;
        x3 = (p3 & 0x8000u) ? x3 : (int)p3;
        p0 = sm.parU[x0]; p1 = sm.parU[x1]; p2 = sm.parU[x2]; p3 = sm.parU[x3];
      }
      // prefetch birth keys + spans of candidate roots (parallel LDS reads)
      const float v0 = keyToFloat(sm.K[(int)(p0 & 0x3FFFu)]);
      const float v1 = keyToFloat(sm.K[(int)(p1 & 0x3FFFu)]);
      const float v2 = keyToFloat(sm.K[(int)(p2 & 0x3FFFu)]);
      const float v3 = keyToFloat(sm.K[(int)(p3 & 0x3FFFu)]);
      const unsigned sp0 = sm.rspan[(int)(p0 & 0x3FFFu)];
      const unsigned sp1 = sm.rspan[(int)(p1 & 0x3FFFu)];
      const unsigned sp2 = sm.rspan[(int)(p2 & 0x3FFFu)];
      const unsigned sp3 = sm.rspan[(int)(p3 & 0x3FFFu)];
      int mv = vid, mr = t;
      float mval = vt;
      unsigned mspan = (unsigned)((r << 8) | r);
      int g0 = -1, g1 = -1, g2 = -1;
      #define DO_CHAIN(pc, xc, vc, sc)                                          \
      {                                                                         \
        const int rr = (int)(pc & 0x3FFFu);                                     \
        const int rv = xc;                                                      \
        if (rr <= t && rv != mv && rv != g0 && rv != g1 && rv != g2) {          \
          int yR, yV; unsigned ySpan; float ybv;                                \
          if (rr > mr) {                                                        \
            yR = rr; yV = rv; ySpan = sc; ybv = vc;                             \
            sm.parU[rv] = (unsigned short)mv;                                   \
          } else {                                                              \
            yR = mr; yV = mv; ySpan = mspan; ybv = mval;                        \
            sm.rspan[mr] = (unsigned short)mspan;                               \
            sm.parU[mv] = (unsigned short)rv;                                   \
            mv = rv; mr = rr; mval = vc;                                        \
          }                                                                     \
          const bool yT = (tTop && (ySpan >> 8) == (unsigned)rtop) ||           \
                          (tBot && (ySpan & 0xFFu) == (unsigned)rbot);          \
          if (yT) {                                                             \
            db[dc * 3 + 0] = (unsigned short)t;                                 \
            db[dc * 3 + 1] = (unsigned short)yR;                                \
            db[dc * 3 + 2] = (unsigned short)mr;                                \
            ++dc;                                                               \
          } else {                                                              \
            const float pers = vt - ybv;                                        \
            if (pers > 0.0f) { T += (double)pers;                               \
                               S += (double)(pers * logf(pers)); }              \
          }                                                                     \
          const unsigned mnn = min(mspan >> 8, sc >> 8);                        \
          const unsigned mxx = max(mspan & 0xFFu, sc & 0xFFu);                  \
          mspan = (mnn << 8) | mxx;                                             \
          g2 = g1; g1 = g0; g0 = yV;                                            \
        }                                                                       \
      }
      DO_CHAIN(p0, x0, v0, sp0)
      DO_CHAIN(p1, x1, v1, sp1)
      DO_CHAIN(p2, x2, v2, sp2)
      DO_CHAIN(p3, x3, v3, sp3)
      #undef DO_CHAIN
      sm.parU[mv] = (unsigned short)(0x8000u | (unsigned int)mr);
      sm.rspan[mr] = (unsigned short)mspan;
      if (vid != mv) sm.parU[vid] = (unsigned short)mv;
      if ((int)(p0 & 0x3FFFu) <= t) { if (n0 != mv) sm.parU[n0] = (unsigned short)mv;
                                      if (x0 != mv && x0 != n0) sm.parU[x0] = (unsigned short)mv; }
      if ((int)(p1 & 0x3FFFu) <= t) { if (n1 != mv) sm.parU[n1] = (unsigned short)mv;
                                      if (x1 != mv && x1 != n1) sm.parU[x1] = (unsigned short)mv; }
      if ((int)(p2 & 0x3FFFu) <= t) { if (n2 != mv) sm.parU[n2] = (unsigned short)mv;
                                      if (x2 != mv && x2 != n2) sm.parU[x2] = (unsigned short)mv; }
      if ((int)(p3 & 0x3FFFu) <= t) { if (n3 != mv) sm.parU[n3] = (unsigned short)mv;
                                      if (x3 != mv && x3 != n3) sm.parU[x3] = (unsigned short)mv; }
      if (r == rbot && b < NBANDS - 1) anchors[b * 192 + c] = (unsigned short)mr;
      if (r == rtop && b > 0)          anchors[(b - 1) * 192 + 96 + c] = (unsigned short)mr;
    }
    sm.accT[b] = T; sm.accS[b] = S; sm.dcnt0[b] = (unsigned int)dc;
  }
  __syncthreads();

  // ---- P6: cut events build + composite-key bitonic (BL arena is dead) ----
  for (int e = tid; e < CUT_N; e += NT) {
    unsigned key = 0xFFFFFFFFu, pay = 0u;
    if (e < NCUTS * 96) {
      const int cut = e / 96;
      const int col = e - cut * 96;
      const unsigned ru = sm.rkB[cut * 192 + col];
      const unsigned rd = sm.rkB[cut * 192 + 96 + col];
      const unsigned wr = ru > rd ? ru : rd;
      key = ((unsigned)cut << 14) | wr;
      pay = ((unsigned)anchors[cut * 192 + col] << 16) | anchors[cut * 192 + 96 + col];
    }
    cutEv[2 * e] = key; cutEv[2 * e + 1] = pay;
  }
  __syncthreads();
  for (int k = 2; k <= CUT_N; k <<= 1) {
    for (int j = k >> 1; j > 0; j >>= 1) {
      const int p = tid;  // exactly 1024 pairs
      const int i = ((p & ~(j - 1)) << 1) | (p & (j - 1));
      const int l = i | j;
      unsigned ki = cutEv[2 * i], kl = cutEv[2 * l];
      unsigned ai = cutEv[2 * i + 1], al = cutEv[2 * l + 1];
      const bool up = ((i & k) == 0);
      const bool sw = up ? (ki > kl) : (ki < kl);
      cutEv[2 * i] = sw ? kl : ki;  cutEv[2 * l] = sw ? ki : kl;
      cutEv[2 * i + 1] = sw ? al : ai;  cutEv[2 * l + 1] = sw ? ai : al;
      __syncthreads();
    }
  }

  // ---- P7: region-tree levels 1..4 ----
  for (int l = 1; l <= 4; ++l) {
    for (int i = tid; i < NV; i += NT) sm.parU[i] = (unsigned short)0x8000u;
    __syncthreads();
    const int nreg = 16 >> l;
    if ((tid & 63) == 0 && (tid >> 6) < nreg) {
      const int g = tid >> 6;
      const int rlo = (g << l) * BROWS, rhi = (((g + 1) << l) * BROWS) - 1;
      const bool tTop = rlo > 0, tBot = rhi < H_ - 1;
      const int cc = (g << l) + (1 << (l - 1)) - 1;
      // output
      unsigned long long* outW = 0; int ocap = 0;
      if (l == 1)      { outW = (unsigned long long*)(w + L1_OFF) + (size_t)g * L1CAP; ocap = L1CAP; }
      else if (l == 2) { outW = (unsigned long long*)(w + L2_OFF) + (size_t)g * L2CAP; ocap = L2CAP; }
      else if (l == 3) { outW = (unsigned long long*)(w + L3_OFF) + (size_t)g * L3CAP; ocap = L3CAP; }
      (void)ocap;
      // input streams
      const unsigned short* dA16 = 0; const unsigned short* dB16 = 0;
      const unsigned long long* dA64 = 0; const unsigned long long* dB64 = 0;
      int cntA, cntB;
      if (l == 1) {
        dA16 = &dfr0[(2 * g) * DCAP * 3];     cntA = (int)sm.dcnt0[2 * g];
        dB16 = &dfr0[(2 * g + 1) * DCAP * 3]; cntB = (int)sm.dcnt0[2 * g + 1];
      } else {
        const int off = (l == 2) ? L1_OFF : (l == 3) ? L2_OFF : L3_OFF;
        const int cap = (l == 2) ? L1CAP : (l == 3) ? L2CAP : L3CAP;
        dA64 = (const unsigned long long*)(w + off) + (size_t)(2 * g) * cap;
        dB64 = (const unsigned long long*)(w + off) + (size_t)(2 * g + 1) * cap;
        cntA = (int)sm.dcntL[l - 2][2 * g];
        cntB = (int)sm.dcntL[l - 2][2 * g + 1];
      }
      int iA = 0, iB = 0, iC = 0;
      unsigned wA, aA, bA, wB, aB, bB, wC, aC, bC;
      #define LOAD_A { if (iA < cntA) { if (l == 1) { const unsigned short* e = &dA16[iA*3]; wA=e[0]; aA=e[1]; bA=e[2]; } \
                        else { const unsigned long long e = dA64[iA]; wA=(unsigned)(e&0xFFFFu); aA=(unsigned)((e>>16)&0xFFFFu); bA=(unsigned)((e>>32)&0xFFFFu); } } else wA = 0xFFFFu; }
      #define LOAD_B { if (iB < cntB) { if (l == 1) { const unsigned short* e = &dB16[iB*3]; wB=e[0]; aB=e[1]; bB=e[2]; } \
                        else { const unsigned long long e = dB64[iB]; wB=(unsigned)(e&0xFFFFu); aB=(unsigned)((e>>16)&0xFFFFu); bB=(unsigned)((e>>32)&0xFFFFu); } } else wB = 0xFFFFu; }
      #define LOAD_C { if (iC < 96) { const unsigned key = cutEv[2*(cc*96+iC)], pay = cutEv[2*(cc*96+iC)+1]; \
                        wC = key & 0x3FFFu; aC = pay >> 16; bC = pay & 0xFFFFu; } else wC = 0xFFFFu; }
      LOAD_A LOAD_B LOAD_C
      double T = 0.0, S = 0.0;
      int dc = 0;
      for (;;) {
        unsigned wm = wA; int s = 0;
        if (wB < wm) { wm = wB; s = 1; }
        if (wC < wm) { wm = wC; s = 2; }
        if (wm == 0xFFFFu) break;
        const int ra = (int)(s == 0 ? aA : s == 1 ? aB : aC);
        const int rb = (int)(s == 0 ? bA : s == 1 ? bB : bC);
        if (s == 0) { ++iA; LOAD_A }
        else if (s == 1) { ++iB; LOAD_B }
        else { ++iC; LOAD_C }
        int fa = ra, fb = rb;
        unsigned ea = sm.parU[fa], eb = sm.parU[fb];
        while (!((ea & eb) & 0x8000u)) {
          fa = (ea & 0x8000u) ? fa : (int)ea;
          fb = (eb & 0x8000u) ? fb : (int)eb;
          ea = sm.parU[fa]; eb = sm.parU[fb];
        }
        if (fa != fb) {
          const int y = fa > fb ? fa : fb;
          const int o = fa + fb - y;
          const unsigned sy = sm.rspan[y], so = sm.rspan[o];
          const bool tn = (tTop && (sy >> 8) == (unsigned)rlo) ||
                          (tBot && (sy & 0xFFu) == (unsigned)rhi);
          if (!tn) {
            const float pers = keyToFloat(sm.K[wm]) - keyToFloat(sm.K[y]);
            if (pers > 0.0f) { T += (double)pers; S += (double)(pers * logf(pers)); }
          } else {
            outW[dc++] = (unsigned long long)wm |
                         ((unsigned long long)(unsigned)o << 16) |
                         ((unsigned long long)(unsigned)y << 32);
          }
          sm.parU[y] = (unsigned short)o;
          const unsigned mnn = min(sy >> 8, so >> 8);
          const unsigned mxx = max(sy & 0xFFu, so & 0xFFu);
          sm.rspan[o] = (unsigned short)((mnn << 8) | mxx);
          if (ra != o && ra != y) sm.parU[ra] = (unsigned short)o;
          if (rb != o && rb != y) sm.parU[rb] = (unsigned short)o;
        } else {
          if (ra != fa) sm.parU[ra] = (unsigned short)fa;
          if (rb != fb) sm.parU[rb] = (unsigned short)fb;
        }
      }
      #undef LOAD_A
      #undef LOAD_B
      #undef LOAD_C
      sm.accT[g] += T; sm.accS[g] += S;
      if (l < 4) sm.dcntL[l - 1][g] = (unsigned int)dc;
    }
    __syncthreads();
  }

  // ---- P8: reduce ----
  if (tid == 0) {
    double T = 0.0, S = 0.0;
    for (int q = 0; q < 16; ++q) { T += sm.accT[q]; S += sm.accS[q]; }
    out[blockIdx.x] = (T > 0.0) ? (float)(log(T) - S / T) : 0.0f;
  }
}

extern "C" void kernel_launch(void* const* d_in, const int* in_sizes, int n_in,
                              void* d_out, int out_size, void* d_ws, size_t ws_size,
                              hipStream_t stream) {
  (void)n_in; (void)out_size;
  const float* x = (const float*)d_in[0];
  float* out = (float*)d_out;
  int n_img = in_sizes[0] / NV;   // 64
  if (n_img <= 0) n_img = 1;
  // ws requirement: 160KB/image = 10.24MB for 64 (available per R11/12: >=12.3MB)
  unsigned char* ws = (unsigned char*)d_ws;
  topo_tree<<<n_img, NT, 0, stream>>>(x, out, ws);
  (void)ws_size;
}

// Round 17
// 2511.336 us; speedup vs baseline: 1.1684x; 1.0061x over previous
//
#include <hip/hip_runtime.h>

#define H_ 96
#define W_ 96
#define NV (H_ * W_)              // 9216
#define SORT_N 16384
#define NT 1024
#define NBANDS 16
#define BROWS 6
#define BVERTS 576
#define DCAP 288                  // proven: deferred/band <= 287
#define NCUTS 15
#define CUT_N 2048

// ws per-image layout (levels 1-3 deferred events, u64 each)
#define WS_STRIDE (160 * 1024)
#define L1_OFF 0                  // 8 regions x 768
#define L2_OFF 49152              // 4 regions x 1536
#define L3_OFF 98304              // 2 regions x 3072
#define L1CAP 768
#define L2CAP 1536
#define L3CAP 3072

__device__ __forceinline__ float keyToFloat(unsigned int k) {
  return __uint_as_float((k & 0x80000000u) ? (k ^ 0x80000000u) : ~k);
}

// LDS: 64K + 32K + 18K + 18K + 18K + 5.6K + 0.4K = 159.8KB <= 160KiB
struct SMem {
  unsigned int   K[SORT_N];        // keys by rank; tail [NV..): dfr0 16x288x3 u16 (27648B)
  unsigned short P[SORT_N];        // rank->vid; tail [NV..): anchors 15x192 u16
  unsigned short parU[NV];         // band phase: vid-indexed UF; levels: rank-indexed U_l
  unsigned short rspan[NV];        // rank-indexed (minrow<<8|maxrow); RESET EVERY LEVEL
  unsigned short BLarena[NV];      // band lists; then cutEv (2048 x {key,pay} u32 = 16KB)
  unsigned short rkB[NCUTS * 192];
  double accT[16], accS[16];
  unsigned int dcnt0[16];
  unsigned int dcntL[3][8];
};

__global__ __launch_bounds__(NT, 1)
void topo_tree(const float* __restrict__ x, float* __restrict__ out,
               unsigned char* __restrict__ ws) {
  __shared__ SMem sm;
  const int tid = threadIdx.x;
  const float* img = x + (size_t)blockIdx.x * NV;
  unsigned char* w = ws + (size_t)blockIdx.x * WS_STRIDE;
  unsigned short* dfr0    = (unsigned short*)&sm.K[NV];
  unsigned short* anchors = &sm.P[NV];
  unsigned short* BL      = sm.BLarena;
  unsigned int*   cutEv   = (unsigned int*)sm.BLarena;

  // ---- P1: order-preserving keys ----
  for (int i = tid; i < SORT_N; i += NT) {
    if (i < NV) {
      unsigned int b = __float_as_uint(img[i]);
      sm.K[i] = b ^ ((b & 0x80000000u) ? 0xFFFFFFFFu : 0x80000000u);
      sm.P[i] = (unsigned short)i;
    } else { sm.K[i] = 0xFFFFFFFFu; sm.P[i] = 0xFFFFu; }
  }
  if (tid < 16) { sm.dcnt0[tid] = 0u; sm.accT[tid] = 0.0; sm.accS[tid] = 0.0; }
  if (tid < 24) ((unsigned int*)sm.dcntL)[tid] = 0u;
  __syncthreads();

  // ---- P2: bitonic sort (K,P) ----
  for (int k = 2; k <= SORT_N; k <<= 1) {
    for (int j = k >> 1; j > 0; j >>= 1) {
      #pragma unroll 4
      for (int p = tid; p < (SORT_N / 2); p += NT) {
        int i = ((p & ~(j - 1)) << 1) | (p & (j - 1));
        int l = i | j;
        unsigned int ki = sm.K[i], kl = sm.K[l];
        unsigned short pi = sm.P[i], pl = sm.P[l];
        bool up = ((i & k) == 0);
        bool sw = up ? (ki > kl) : (ki < kl);
        sm.K[i] = sw ? kl : ki;  sm.K[l] = sw ? ki : kl;
        sm.P[i] = sw ? pl : pi;  sm.P[l] = sw ? pi : pl;
      }
      __syncthreads();
    }
  }

  // ---- P3: scatter init: parU[vid]=root(rank), rspan[rank]=row, rkB ----
  for (int t = tid; t < NV; t += NT) {
    const int vid = (int)sm.P[t];
    sm.parU[vid] = (unsigned short)(0x8000u | (unsigned int)t);
    const int r = vid / W_;
    const int c = vid - r * W_;
    sm.rspan[t] = (unsigned short)((r << 8) | r);
    if ((r % BROWS) == BROWS - 1 && r < H_ - 1) sm.rkB[(r / BROWS) * 192 + c] = (unsigned short)t;
    if ((r % BROWS) == 0 && r > 0)              sm.rkB[(r / BROWS - 1) * 192 + 96 + c] = (unsigned short)t;
  }
  // ---- P4: band lists ----
  {
    const int wv = tid >> 6, lane = tid & 63;
    int cnt = 0;
    for (int t0 = 0; t0 < NV; t0 += 64) {
      const int t = t0 + lane;
      const int vid = (int)sm.P[t];
      const bool mine = (vid / BVERTS) == wv;
      const unsigned long long m = __ballot(mine);
      if (mine)
        BL[wv * BVERTS + cnt + __popcll(m & ((1ull << lane) - 1ull))] = (unsigned short)t;
      cnt += (int)__popcll(m);
    }
  }
  __syncthreads();

  // ---- P5: 16-band parallel Kruskal with rowspan taint ----
  if ((tid & 63) == 0) {
    const int b = tid >> 6;
    const int base = b * BVERTS;
    const int rtop = b * BROWS, rbot = rtop + BROWS - 1;
    const bool tTop = (b > 0), tBot = (b < NBANDS - 1);
    unsigned short* db = &dfr0[b * DCAP * 3];
    double T = 0.0, S = 0.0;
    int dc = 0;
    int t_n = (int)BL[base];
    for (int j = 0; j < BVERTS; ++j) {
      const int t = t_n;
      if (j + 1 < BVERTS) t_n = (int)BL[base + j + 1];
      const int vid = (int)sm.P[t];
      const float vt = keyToFloat(sm.K[t]);
      const int r = vid / W_;
      const int c = vid - r * W_;
      int n0 = (c > 0)      ? vid - 1  : vid;
      int n1 = (c < W_ - 1) ? vid + 1  : vid;
      int n2 = (r > rtop)   ? vid - W_ : vid;
      int n3 = (r < rbot)   ? vid + W_ : vid;
      int x0 = n0, x1 = n1, x2 = n2, x3 = n3;
      unsigned int p0 = sm.parU[x0], p1 = sm.parU[x1], p2 = sm.parU[x2], p3 = sm.parU[x3];
      const unsigned int self = 0x8000u | (unsigned int)t;
      if ((p0 & 0x8000u) && (int)(p0 & 0x3FFFu) > t) { x0 = vid; n0 = vid; p0 = self; }
      if ((p1 & 0x8000u) && (int)(p1 & 0x3FFFu) > t) { x1 = vid; n1 = vid; p1 = self; }
      if ((p2 & 0x8000u) && (int)(p2 & 0x3FFFu) > t) { x2 = vid; n2 = vid; p2 = self; }
      if ((p3 & 0x8000u) && (int)(p3 & 0x3FFFu) > t) { x3 = vid; n3 = vid; p3 = self; }
      while (!((p0 & p1 & p2 & p3) & 0x8000u)) {
        x0 = (p0 & 0x8000u) ? x0 : (int)p0;
        x1 = (p1 & 0x8000u) ? x1 : (int)p1;
        x2 = (p2 & 0x8000u) ? x2 : (int)p2;
        x3 = (p3 & 0x8000u) ? x3 : (int)p3;
        p0 = sm.parU[x0]; p1 = sm.parU[x1]; p2 = sm.parU[x2]; p3 = sm.parU[x3];
      }
      // prefetch birth keys + spans of candidate roots (parallel LDS reads)
      const float v0 = keyToFloat(sm.K[(int)(p0 & 0x3FFFu)]);
      const float v1 = keyToFloat(sm.K[(int)(p1 & 0x3FFFu)]);
      const float v2 = keyToFloat(sm.K[(int)(p2 & 0x3FFFu)]);
      const float v3 = keyToFloat(sm.K[(int)(p3 & 0x3FFFu)]);
      const unsigned sp0 = sm.rspan[(int)(p0 & 0x3FFFu)];
      const unsigned sp1 = sm.rspan[(int)(p1 & 0x3FFFu)];
      const unsigned sp2 = sm.rspan[(int)(p2 & 0x3FFFu)];
      const unsigned sp3 = sm.rspan[(int)(p3 & 0x3FFFu)];
      int mv = vid, mr = t;
      float mval = vt;
      unsigned mspan = (unsigned)((r << 8) | r);
      int g0 = -1, g1 = -1, g2 = -1;
      #define DO_CHAIN(pc, xc, vc, sc)                                          \
      {                                                                         \
        const int rr = (int)(pc & 0x3FFFu);                                     \
        const int rv = xc;                                                      \
        if (rr <= t && rv != mv && rv != g0 && rv != g1 && rv != g2) {          \
          int yR, yV; unsigned ySpan; float ybv;                                \
          if (rr > mr) {                                                        \
            yR = rr; yV = rv; ySpan = sc; ybv = vc;                             \
            sm.parU[rv] = (unsigned short)mv;                                   \
          } else {                                                              \
            yR = mr; yV = mv; ySpan = mspan; ybv = mval;                        \
            sm.rspan[mr] = (unsigned short)mspan;                               \
            sm.parU[mv] = (unsigned short)rv;                                   \
            mv = rv; mr = rr; mval = vc;                                        \
          }                                                                     \
          const bool yT = (tTop && (ySpan >> 8) == (unsigned)rtop) ||           \
                          (tBot && (ySpan & 0xFFu) == (unsigned)rbot);          \
          if (yT) {                                                             \
            db[dc * 3 + 0] = (unsigned short)t;                                 \
            db[dc * 3 + 1] = (unsigned short)yR;                                \
            db[dc * 3 + 2] = (unsigned short)mr;                                \
            ++dc;                                                               \
          } else {                                                              \
            const float pers = vt - ybv;                                        \
            if (pers > 0.0f) { T += (double)pers;                               \
                               S += (double)(pers * logf(pers)); }              \
          }                                                                     \
          const unsigned mnn = min(mspan >> 8, sc >> 8);                        \
          const unsigned mxx = max(mspan & 0xFFu, sc & 0xFFu);                  \
          mspan = (mnn << 8) | mxx;                                             \
          g2 = g1; g1 = g0; g0 = yV;                                            \
        }                                                                       \
      }
      DO_CHAIN(p0, x0, v0, sp0)
      DO_CHAIN(p1, x1, v1, sp1)
      DO_CHAIN(p2, x2, v2, sp2)
      DO_CHAIN(p3, x3, v3, sp3)
      #undef DO_CHAIN
      sm.parU[mv] = (unsigned short)(0x8000u | (unsigned int)mr);
      sm.rspan[mr] = (unsigned short)mspan;
      if (vid != mv) sm.parU[vid] = (unsigned short)mv;
      if ((int)(p0 & 0x3FFFu) <= t) { if (n0 != mv) sm.parU[n0] = (unsigned short)mv;
                                      if (x0 != mv && x0 != n0) sm.parU[x0] = (unsigned short)mv; }
      if ((int)(p1 & 0x3FFFu) <= t) { if (n1 != mv) sm.parU[n1] = (unsigned short)mv;
                                      if (x1 != mv && x1 != n1) sm.parU[x1] = (unsigned short)mv; }
      if ((int)(p2 & 0x3FFFu) <= t) { if (n2 != mv) sm.parU[n2] = (unsigned short)mv;
                                      if (x2 != mv && x2 != n2) sm.parU[x2] = (unsigned short)mv; }
      if ((int)(p3 & 0x3FFFu) <= t) { if (n3 != mv) sm.parU[n3] = (unsigned short)mv;
                                      if (x3 != mv && x3 != n3) sm.parU[x3] = (unsigned short)mv; }
      if (r == rbot && b < NBANDS - 1) anchors[b * 192 + c] = (unsigned short)mr;
      if (r == rtop && b > 0)          anchors[(b - 1) * 192 + 96 + c] = (unsigned short)mr;
    }
    sm.accT[b] = T; sm.accS[b] = S; sm.dcnt0[b] = (unsigned int)dc;
  }
  __syncthreads();

  // ---- P6: cut events build + composite-key bitonic (BL arena is dead) ----
  for (int e = tid; e < CUT_N; e += NT) {
    unsigned key = 0xFFFFFFFFu, pay = 0u;
    if (e < NCUTS * 96) {
      const int cut = e / 96;
      const int col = e - cut * 96;
      const unsigned ru = sm.rkB[cut * 192 + col];
      const unsigned rd = sm.rkB[cut * 192 + 96 + col];
      const unsigned wr = ru > rd ? ru : rd;
      key = ((unsigned)cut << 14) | wr;
      pay = ((unsigned)anchors[cut * 192 + col] << 16) | anchors[cut * 192 + 96 + col];
    }
    cutEv[2 * e] = key; cutEv[2 * e + 1] = pay;
  }
  __syncthreads();
  for (int k = 2; k <= CUT_N; k <<= 1) {
    for (int j = k >> 1; j > 0; j >>= 1) {
      const int p = tid;  // exactly 1024 pairs
      const int i = ((p & ~(j - 1)) << 1) | (p & (j - 1));
      const int l = i | j;
      unsigned ki = cutEv[2 * i], kl = cutEv[2 * l];
      unsigned ai = cutEv[2 * i + 1], al = cutEv[2 * l + 1];
      const bool up = ((i & k) == 0);
      const bool sw = up ? (ki > kl) : (ki < kl);
      cutEv[2 * i] = sw ? kl : ki;  cutEv[2 * l] = sw ? ki : kl;
      cutEv[2 * i + 1] = sw ? al : ai;  cutEv[2 * l + 1] = sw ? ai : al;
      __syncthreads();
    }
  }

  // ---- P7: region-tree levels 1..4 ----
  for (int l = 1; l <= 4; ++l) {
    // reset UF AND rspan each level: spans must be reconstructed within-level
    // (stale wide spans from the previous level over-taint and kill decay).
    for (int t = tid; t < NV; t += NT) {
      sm.parU[t] = (unsigned short)0x8000u;
      const int r = (int)sm.P[t] / W_;
      sm.rspan[t] = (unsigned short)((r << 8) | r);
    }
    __syncthreads();
    const int nreg = 16 >> l;
    if ((tid & 63) == 0 && (tid >> 6) < nreg) {
      const int g = tid >> 6;
      const int rlo = (g << l) * BROWS, rhi = (((g + 1) << l) * BROWS) - 1;
      const bool tTop = rlo > 0, tBot = rhi < H_ - 1;
      const int cc = (g << l) + (1 << (l - 1)) - 1;
      // output
      unsigned long long* outW = 0;
      if (l == 1)      outW = (unsigned long long*)(w + L1_OFF) + (size_t)g * L1CAP;
      else if (l == 2) outW = (unsigned long long*)(w + L2_OFF) + (size_t)g * L2CAP;
      else if (l == 3) outW = (unsigned long long*)(w + L3_OFF) + (size_t)g * L3CAP;
      // input streams
      const unsigned short* dA16 = 0; const unsigned short* dB16 = 0;
      const unsigned long long* dA64 = 0; const unsigned long long* dB64 = 0;
      int cntA, cntB;
      if (l == 1) {
        dA16 = &dfr0[(2 * g) * DCAP * 3];     cntA = (int)sm.dcnt0[2 * g];
        dB16 = &dfr0[(2 * g + 1) * DCAP * 3]; cntB = (int)sm.dcnt0[2 * g + 1];
      } else {
        const int off = (l == 2) ? L1_OFF : (l == 3) ? L2_OFF : L3_OFF;
        const int cap = (l == 2) ? L1CAP : (l == 3) ? L2CAP : L3CAP;
        dA64 = (const unsigned long long*)(w + off) + (size_t)(2 * g) * cap;
        dB64 = (const unsigned long long*)(w + off) + (size_t)(2 * g + 1) * cap;
        cntA = (int)sm.dcntL[l - 2][2 * g];
        cntB = (int)sm.dcntL[l - 2][2 * g + 1];
      }
      int iA = 0, iB = 0, iC = 0;
      unsigned wA, aA, bA, wB, aB, bB, wC, aC, bC;
      #define LOAD_A { if (iA < cntA) { if (l == 1) { const unsigned short* e = &dA16[iA*3]; wA=e[0]; aA=e[1]; bA=e[2]; } \
                        else { const unsigned long long e = dA64[iA]; wA=(unsigned)(e&0xFFFFu); aA=(unsigned)((e>>16)&0xFFFFu); bA=(unsigned)((e>>32)&0xFFFFu); } } else wA = 0xFFFFu; }
      #define LOAD_B { if (iB < cntB) { if (l == 1) { const unsigned short* e = &dB16[iB*3]; wB=e[0]; aB=e[1]; bB=e[2]; } \
                        else { const unsigned long long e = dB64[iB]; wB=(unsigned)(e&0xFFFFu); aB=(unsigned)((e>>16)&0xFFFFu); bB=(unsigned)((e>>32)&0xFFFFu); } } else wB = 0xFFFFu; }
      #define LOAD_C { if (iC < 96) { const unsigned key = cutEv[2*(cc*96+iC)], pay = cutEv[2*(cc*96+iC)+1]; \
                        wC = key & 0x3FFFu; aC = pay >> 16; bC = pay & 0xFFFFu; } else wC = 0xFFFFu; }
      LOAD_A LOAD_B LOAD_C
      double T = 0.0, S = 0.0;
      int dc = 0;
      for (;;) {
        unsigned wm = wA; int s = 0;
        if (wB < wm) { wm = wB; s = 1; }
        if (wC < wm) { wm = wC; s = 2; }
        if (wm == 0xFFFFu) break;
        const int ra = (int)(s == 0 ? aA : s == 1 ? aB : aC);
        const int rb = (int)(s == 0 ? bA : s == 1 ? bB : bC);
        if (s == 0) { ++iA; LOAD_A }
        else if (s == 1) { ++iB; LOAD_B }
        else { ++iC; LOAD_C }
        int fa = ra, fb = rb;
        unsigned ea = sm.parU[fa], eb = sm.parU[fb];
        while (!((ea & eb) & 0x8000u)) {
          fa = (ea & 0x8000u) ? fa : (int)ea;
          fb = (eb & 0x8000u) ? fb : (int)eb;
          ea = sm.parU[fa]; eb = sm.parU[fb];
        }
        if (fa != fb) {
          const int y = fa > fb ? fa : fb;
          const int o = fa + fb - y;
          const unsigned sy = sm.rspan[y], so = sm.rspan[o];
          const bool tn = (tTop && (sy >> 8) == (unsigned)rlo) ||
                          (tBot && (sy & 0xFFu) == (unsigned)rhi);
          if (!tn) {
            const float pers = keyToFloat(sm.K[wm]) - keyToFloat(sm.K[y]);
            if (pers > 0.0f) { T += (double)pers; S += (double)(pers * logf(pers)); }
          } else {
            outW[dc++] = (unsigned long long)wm |
                         ((unsigned long long)(unsigned)o << 16) |
                         ((unsigned long long)(unsigned)y << 32);
          }
          sm.parU[y] = (unsigned short)o;
          const unsigned mnn = min(sy >> 8, so >> 8);
          const unsigned mxx = max(sy & 0xFFu, so & 0xFFu);
          sm.rspan[o] = (unsigned short)((mnn << 8) | mxx);
          if (ra != o && ra != y) sm.parU[ra] = (unsigned short)o;
          if (rb != o && rb != y) sm.parU[rb] = (unsigned short)o;
        } else {
          if (ra != fa) sm.parU[ra] = (unsigned short)fa;
          if (rb != fb) sm.parU[rb] = (unsigned short)fb;
        }
      }
      #undef LOAD_A
      #undef LOAD_B
      #undef LOAD_C
      sm.accT[g] += T; sm.accS[g] += S;
      if (l < 4) sm.dcntL[l - 1][g] = (unsigned int)dc;
    }
    __syncthreads();
  }

  // ---- P8: reduce ----
  if (tid == 0) {
    double T = 0.0, S = 0.0;
    for (int q = 0; q < 16; ++q) { T += sm.accT[q]; S += sm.accS[q]; }
    out[blockIdx.x] = (T > 0.0) ? (float)(log(T) - S / T) : 0.0f;
  }
}

extern "C" void kernel_launch(void* const* d_in, const int* in_sizes, int n_in,
                              void* d_out, int out_size, void* d_ws, size_t ws_size,
                              hipStream_t stream) {
  (void)n_in; (void)out_size;
  const float* x = (const float*)d_in[0];
  float* out = (float*)d_out;
  int n_img = in_sizes[0] / NV;   // 64
  if (n_img <= 0) n_img = 1;
  unsigned char* ws = (unsigned char*)d_ws;
  topo_tree<<<n_img, NT, 0, stream>>>(x, out, ws);
  (void)ws_size;
}

// Round 18
// 735.155 us; speedup vs baseline: 3.9912x; 3.4161x over previous
//
#include <hip/hip_runtime.h>

#define H_ 96
#define W_ 96
#define NV (H_ * W_)      // 9216
#define SORT_N 16384
#define NT 1024

// LDS: 65536 + 32768 + 18432 + 36864 = 153600 B <= 160 KiB
struct SMem {
  unsigned int   K[SORT_N];      // rank -> sortable key
  unsigned short P[SORT_N];      // rank -> vid
  unsigned short parU[NV];       // vid -> parent vid, or 0x8000|rank if root (root = min rank)
  unsigned int   claim[NV];      // demote-claim table (lane ids), kept all-0xFFFFFFFF between rounds
};

__device__ __forceinline__ float keyToFloat(unsigned int k) {
  return __uint_as_float((k & 0x80000000u) ? (k ^ 0x80000000u) : ~k);
}
__device__ __forceinline__ unsigned int bitsToKey(unsigned int b) {
  return b ^ ((b & 0x80000000u) ? 0xFFFFFFFFu : 0x80000000u);
}

__global__ __launch_bounds__(NT, 1)
void topo_pk(const float* __restrict__ x, float* __restrict__ out) {
  __shared__ SMem sm;
  const int tid = threadIdx.x;
  const float* img = x + (size_t)blockIdx.x * NV;

  // ---- P1: order-preserving keys ----
  for (int i = tid; i < SORT_N; i += NT) {
    if (i < NV) { sm.K[i] = bitsToKey(__float_as_uint(img[i])); sm.P[i] = (unsigned short)i; }
    else        { sm.K[i] = 0xFFFFFFFFu; sm.P[i] = 0xFFFFu; }
  }
  __syncthreads();

  // ---- P2: bitonic sort (K,P) ascending ----
  for (int k = 2; k <= SORT_N; k <<= 1) {
    for (int j = k >> 1; j > 0; j >>= 1) {
      #pragma unroll 4
      for (int p = tid; p < (SORT_N / 2); p += NT) {
        int i = ((p & ~(j - 1)) << 1) | (p & (j - 1));
        int l = i | j;
        unsigned ki = sm.K[i], kl = sm.K[l];
        unsigned short pi = sm.P[i], pl = sm.P[l];
        bool up = ((i & k) == 0);
        bool sw = up ? (ki > kl) : (ki < kl);
        sm.K[i] = sw ? kl : ki;  sm.K[l] = sw ? ki : kl;
        sm.P[i] = sw ? pl : pi;  sm.P[l] = sw ? pi : pl;
      }
      __syncthreads();
    }
  }

  // ---- P3: UF init (all vertices pre-inserted as singleton roots) + claim init ----
  for (int t = tid; t < NV; t += NT) sm.parU[sm.P[t]] = (unsigned short)(0x8000u | (unsigned)t);
  for (int i = tid; i < NV; i += NT) sm.claim[i] = 0xFFFFFFFFu;
  __syncthreads();

  // ---- P4: wave-0 parallel-commit Kruskal over ranks ----
  if (tid < 64) {
    const int lane = tid;
    double T = 0.0, S = 0.0;
    for (int ch = 0; ch < NV / 64; ++ch) {
      const int t = ch * 64 + lane;
      const int vid = (int)sm.P[t];
      const unsigned keyT = sm.K[t];
      const float vt = keyToFloat(keyT);
      const int r = vid / W_, c = vid - r * W_;
      const int nv0 = vid - 1, nv1 = vid + 1, nv2 = vid - W_, nv3 = vid + W_;
      const bool bb0 = (c > 0), bb1 = (c < W_ - 1), bb2 = (r > 0), bb3 = (r < H_ - 1);
      // inclusion by VALUE (immune to UF state); equal keys -> both sides process (2nd is a cycle)
      const unsigned kk0 = bb0 ? bitsToKey(__float_as_uint(img[nv0])) : 0xFFFFFFFFu;
      const unsigned kk1 = bb1 ? bitsToKey(__float_as_uint(img[nv1])) : 0xFFFFFFFFu;
      const unsigned kk2 = bb2 ? bitsToKey(__float_as_uint(img[nv2])) : 0xFFFFFFFFu;
      const unsigned kk3 = bb3 ? bitsToKey(__float_as_uint(img[nv3])) : 0xFFFFFFFFu;
      const bool inc0 = bb0 && (kk0 <= keyT);
      const bool inc1 = bb1 && (kk1 <= keyT);
      const bool inc2 = bb2 && (kk2 <= keyT);
      const bool inc3 = bb3 && (kk3 <= keyT);
      int x0 = inc0 ? nv0 : vid, x1 = inc1 ? nv1 : vid;
      int x2 = inc2 ? nv2 : vid, x3 = inc3 ? nv3 : vid;
      unsigned e0 = 0, e1 = 0, e2 = 0, e3 = 0;
      bool committed = false;

      for (;;) {
        if (__ballot(!committed) == 0ull) break;   // uniform exit
        // phase B: interleaved root chase (continues from last positions)
        if (!committed) {
          bool d0 = !inc0, d1 = !inc1, d2 = !inc2, d3 = !inc3;
          while (!(d0 && d1 && d2 && d3)) {
            if (!d0) { unsigned e = sm.parU[x0]; if (e & 0x8000u) { e0 = e; d0 = true; } else x0 = (int)e; }
            if (!d1) { unsigned e = sm.parU[x1]; if (e & 0x8000u) { e1 = e; d1 = true; } else x1 = (int)e; }
            if (!d2) { unsigned e = sm.parU[x2]; if (e & 0x8000u) { e2 = e; d2 = true; } else x2 = (int)e; }
            if (!d3) { unsigned e = sm.parU[x3]; if (e & 0x8000u) { e3 = e; d3 = true; } else x3 = (int)e; }
          }
          // start-compression (phase-ordered before any commit this round)
          if (inc0 && nv0 != x0) sm.parU[nv0] = (unsigned short)x0;
          if (inc1 && nv1 != x1) sm.parU[nv1] = (unsigned short)x1;
          if (inc2 && nv2 != x2) sm.parU[nv2] = (unsigned short)x2;
          if (inc3 && nv3 != x3) sm.parU[nv3] = (unsigned short)x3;
        }
        // phase C: survivor, dedupe, demote set, claims
        bool u0 = false, u1 = false, u2 = false, u3 = false, uv = false;
        int mvid = vid, mrank = t;
        int rr0 = 0, rr1 = 0, rr2 = 0, rr3 = 0;
        if (!committed) {
          rr0 = (int)(e0 & 0x3FFFu); rr1 = (int)(e1 & 0x3FFFu);
          rr2 = (int)(e2 & 0x3FFFu); rr3 = (int)(e3 & 0x3FFFu);
          if (inc0 && rr0 < mrank) { mrank = rr0; mvid = x0; }
          if (inc1 && rr1 < mrank) { mrank = rr1; mvid = x1; }
          if (inc2 && rr2 < mrank) { mrank = rr2; mvid = x2; }
          if (inc3 && rr3 < mrank) { mrank = rr3; mvid = x3; }
          u0 = inc0 && (x0 != mvid);
          u1 = inc1 && (x1 != mvid) && !(inc0 && x1 == x0);
          u2 = inc2 && (x2 != mvid) && !(inc0 && x2 == x0) && !(inc1 && x2 == x1);
          u3 = inc3 && (x3 != mvid) && !(inc0 && x3 == x0) && !(inc1 && x3 == x1) && !(inc2 && x3 == x2);
          uv = (mvid != vid);
          if (u0) atomicMin(&sm.claim[x0], (unsigned)lane);
          if (u1) atomicMin(&sm.claim[x1], (unsigned)lane);
          if (u2) atomicMin(&sm.claim[x2], (unsigned)lane);
          if (u3) atomicMin(&sm.claim[x3], (unsigned)lane);
          if (uv) atomicMin(&sm.claim[vid], (unsigned)lane);
        }
        asm volatile("s_waitcnt lgkmcnt(0)" ::: "memory");
        // phase D: win check (own every slot you will write)
        bool win = !committed;
        if (!committed) {
          if (u0 && sm.claim[x0] != (unsigned)lane) win = false;
          if (u1 && sm.claim[x1] != (unsigned)lane) win = false;
          if (u2 && sm.claim[x2] != (unsigned)lane) win = false;
          if (u3 && sm.claim[x3] != (unsigned)lane) win = false;
          if (uv && sm.claim[vid] != (unsigned)lane) win = false;
        }
        // phase E: commit (parallel across winners; claimed slots are exclusive)
        if (win) {
          if (u0) { const float p = vt - keyToFloat(sm.K[rr0]);
                    if (p > 0.0f) { T += (double)p; S += (double)(p * logf(p)); }
                    sm.parU[x0] = (unsigned short)mvid; }
          if (u1) { const float p = vt - keyToFloat(sm.K[rr1]);
                    if (p > 0.0f) { T += (double)p; S += (double)(p * logf(p)); }
                    sm.parU[x1] = (unsigned short)mvid; }
          if (u2) { const float p = vt - keyToFloat(sm.K[rr2]);
                    if (p > 0.0f) { T += (double)p; S += (double)(p * logf(p)); }
                    sm.parU[x2] = (unsigned short)mvid; }
          if (u3) { const float p = vt - keyToFloat(sm.K[rr3]);
                    if (p > 0.0f) { T += (double)p; S += (double)(p * logf(p)); }
                    sm.parU[x3] = (unsigned short)mvid; }
          if (uv) sm.parU[vid] = (unsigned short)mvid;
          committed = true;
        }
        // phase F: reset claims (winners and losers restore their slots)
        if (u0) sm.claim[x0] = 0xFFFFFFFFu;
        if (u1) sm.claim[x1] = 0xFFFFFFFFu;
        if (u2) sm.claim[x2] = 0xFFFFFFFFu;
        if (u3) sm.claim[x3] = 0xFFFFFFFFu;
        if (uv) sm.claim[vid] = 0xFFFFFFFFu;
        asm volatile("s_waitcnt lgkmcnt(0)" ::: "memory");
      }
    }
    // reduce entropy accumulators across wave 0
    #pragma unroll
    for (int off = 32; off > 0; off >>= 1) {
      T += __shfl_down(T, off, 64);
      S += __shfl_down(S, off, 64);
    }
    if (lane == 0)
      out[blockIdx.x] = (T > 0.0) ? (float)(log(T) - S / T) : 0.0f;
  }
}

extern "C" void kernel_launch(void* const* d_in, const int* in_sizes, int n_in,
                              void* d_out, int out_size, void* d_ws, size_t ws_size,
                              hipStream_t stream) {
  (void)n_in; (void)out_size; (void)d_ws; (void)ws_size;
  const float* x = (const float*)d_in[0];
  float* out = (float*)d_out;
  int n_img = in_sizes[0] / NV;   // 64
  if (n_img <= 0) n_img = 1;
  topo_pk<<<n_img, NT, 0, stream>>>(x, out);
}

// Round 19
// 559.132 us; speedup vs baseline: 5.2477x; 1.3148x over previous
//
#include <hip/hip_runtime.h>

#define H_ 96
#define W_ 96
#define NV (H_ * W_)      // 9216 = 9 * 1024
#define NT 1024
#define NPT 9             // elements per thread (contiguous chunk)

// arena layout (bytes):
//  Ka    @ 0       u32[9216]  (36864)
//  Kb    @ 36864   u32[9216]  (36864)
//  Pa    @ 73728   u16[9216]  (18432)
//  Pb    @ 92160   u16[9216]  (18432)   -> reused as parU in P4
//  hist  @ 110592  u16[16*1024] (32768) -> reused as claim (u32[9216]=36864) in P4
//  total arena = 147456 B; + waveTot/digitBase 128 B  <= 160 KiB
#define ARENA_BYTES 147456

__device__ __forceinline__ float keyToFloat(unsigned int k) {
  return __uint_as_float((k & 0x80000000u) ? (k ^ 0x80000000u) : ~k);
}
__device__ __forceinline__ unsigned int bitsToKey(unsigned int b) {
  return b ^ ((b & 0x80000000u) ? 0xFFFFFFFFu : 0x80000000u);
}

__global__ __launch_bounds__(NT, 1)
void topo_pk(const float* __restrict__ x, float* __restrict__ out) {
  __shared__ unsigned int arenaW[ARENA_BYTES / 4];
  __shared__ unsigned int waveTot[16];
  __shared__ unsigned int digitBase[16];
  unsigned char* arena = (unsigned char*)arenaW;
  unsigned int*   Ka   = (unsigned int*)(arena);
  unsigned int*   Kb   = (unsigned int*)(arena + 36864);
  unsigned short* Pa   = (unsigned short*)(arena + 73728);
  unsigned short* Pb   = (unsigned short*)(arena + 92160);
  unsigned short* hist = (unsigned short*)(arena + 110592);
  unsigned short* parU = (unsigned short*)(arena + 92160);    // P4 (Pb dead)
  unsigned int*   claim = (unsigned int*)(arena + 110592);    // P4 (hist dead)

  const int tid = threadIdx.x;
  const float* img = x + (size_t)blockIdx.x * NV;

  // ---- P1: order-preserving keys + identity payload ----
  for (int i = tid; i < NV; i += NT) {
    Ka[i] = bitsToKey(__float_as_uint(img[i]));
    Pa[i] = (unsigned short)i;
  }
  __syncthreads();

  // ---- P2: 8-pass 4-bit LSD radix sort (stable; thread-contiguous chunks) ----
  for (int pass = 0; pass < 8; ++pass) {
    const unsigned int*   Ks = (pass & 1) ? Kb : Ka;
    const unsigned short* Ps = (pass & 1) ? Pb : Pa;
    unsigned int*   Kd = (pass & 1) ? Ka : Kb;
    unsigned short* Pd = (pass & 1) ? Pa : Pb;
    const int sh = pass << 2;
    const int base = tid * NPT;

    #pragma unroll
    for (int d = 0; d < 16; ++d) hist[d * NT + tid] = 0;
    // count into own column (no cross-thread access -> no barrier needed after zero)
    #pragma unroll
    for (int j = 0; j < NPT; ++j) {
      const unsigned d = (Ks[base + j] >> sh) & 15u;
      hist[d * NT + tid] = (unsigned short)(hist[d * NT + tid] + 1);
    }
    __syncthreads();

    // scan: wave w handles digit w; lane l owns entries [l*16, l*16+16)
    {
      const int wv = tid >> 6, ln = tid & 63;
      const int idx = wv * NT + ln * 16;
      unsigned run = 0;
      #pragma unroll
      for (int j = 0; j < 16; ++j) {
        const unsigned v = hist[idx + j];
        hist[idx + j] = (unsigned short)run;
        run += v;
      }
      // wave-wide inclusive scan of per-lane totals
      unsigned val = run;
      #pragma unroll
      for (int off = 1; off < 64; off <<= 1) {
        const unsigned n = (unsigned)__shfl_up((int)val, off, 64);
        if (ln >= off) val += n;
      }
      const unsigned excl = val - run;
      if (ln == 63) waveTot[wv] = val;
      __syncthreads();
      if (tid < 16) {
        unsigned s = 0;
        for (int d2 = 0; d2 < 16; ++d2) if (d2 < tid) s += waveTot[d2];
        digitBase[tid] = s;
      }
      __syncthreads();
      const unsigned addv = digitBase[wv] + excl;
      #pragma unroll
      for (int j = 0; j < 16; ++j)
        hist[idx + j] = (unsigned short)(hist[idx + j] + addv);
    }
    __syncthreads();

    // stable in-order scatter (own hist column as running offsets)
    #pragma unroll
    for (int j = 0; j < NPT; ++j) {
      const unsigned k = Ks[base + j];
      const unsigned short pv = Ps[base + j];
      const unsigned d = (k >> sh) & 15u;
      const int slot = d * NT + tid;
      const unsigned dest = hist[slot];
      hist[slot] = (unsigned short)(dest + 1);
      Kd[dest] = k;
      Pd[dest] = pv;
    }
    __syncthreads();
  }
  // after 8 passes data is back in Ka / Pa

  // ---- P3: UF init + claim init ----
  for (int t = tid; t < NV; t += NT) parU[Pa[t]] = (unsigned short)(0x8000u | (unsigned)t);
  for (int i = tid; i < NV; i += NT) claim[i] = 0xFFFFFFFFu;
  __syncthreads();

  // ---- P4: wave-0 parallel-commit Kruskal over ranks (verbatim from R18) ----
  if (tid < 64) {
    const int lane = tid;
    double T = 0.0, S = 0.0;
    for (int ch = 0; ch < NV / 64; ++ch) {
      const int t = ch * 64 + lane;
      const int vid = (int)Pa[t];
      const unsigned keyT = Ka[t];
      const float vt = keyToFloat(keyT);
      const int r = vid / W_, c = vid - r * W_;
      const int nv0 = vid - 1, nv1 = vid + 1, nv2 = vid - W_, nv3 = vid + W_;
      const bool bb0 = (c > 0), bb1 = (c < W_ - 1), bb2 = (r > 0), bb3 = (r < H_ - 1);
      const unsigned kk0 = bb0 ? bitsToKey(__float_as_uint(img[nv0])) : 0xFFFFFFFFu;
      const unsigned kk1 = bb1 ? bitsToKey(__float_as_uint(img[nv1])) : 0xFFFFFFFFu;
      const unsigned kk2 = bb2 ? bitsToKey(__float_as_uint(img[nv2])) : 0xFFFFFFFFu;
      const unsigned kk3 = bb3 ? bitsToKey(__float_as_uint(img[nv3])) : 0xFFFFFFFFu;
      const bool inc0 = bb0 && (kk0 <= keyT);
      const bool inc1 = bb1 && (kk1 <= keyT);
      const bool inc2 = bb2 && (kk2 <= keyT);
      const bool inc3 = bb3 && (kk3 <= keyT);
      int x0 = inc0 ? nv0 : vid, x1 = inc1 ? nv1 : vid;
      int x2 = inc2 ? nv2 : vid, x3 = inc3 ? nv3 : vid;
      unsigned e0 = 0, e1 = 0, e2 = 0, e3 = 0;
      bool committed = false;

      for (;;) {
        if (__ballot(!committed) == 0ull) break;
        if (!committed) {
          bool d0 = !inc0, d1 = !inc1, d2 = !inc2, d3 = !inc3;
          while (!(d0 && d1 && d2 && d3)) {
            if (!d0) { unsigned e = parU[x0]; if (e & 0x8000u) { e0 = e; d0 = true; } else x0 = (int)e; }
            if (!d1) { unsigned e = parU[x1]; if (e & 0x8000u) { e1 = e; d1 = true; } else x1 = (int)e; }
            if (!d2) { unsigned e = parU[x2]; if (e & 0x8000u) { e2 = e; d2 = true; } else x2 = (int)e; }
            if (!d3) { unsigned e = parU[x3]; if (e & 0x8000u) { e3 = e; d3 = true; } else x3 = (int)e; }
          }
          if (inc0 && nv0 != x0) parU[nv0] = (unsigned short)x0;
          if (inc1 && nv1 != x1) parU[nv1] = (unsigned short)x1;
          if (inc2 && nv2 != x2) parU[nv2] = (unsigned short)x2;
          if (inc3 && nv3 != x3) parU[nv3] = (unsigned short)x3;
        }
        bool u0 = false, u1 = false, u2 = false, u3 = false, uv = false;
        int mvid = vid, mrank = t;
        int rr0 = 0, rr1 = 0, rr2 = 0, rr3 = 0;
        if (!committed) {
          rr0 = (int)(e0 & 0x3FFFu); rr1 = (int)(e1 & 0x3FFFu);
          rr2 = (int)(e2 & 0x3FFFu); rr3 = (int)(e3 & 0x3FFFu);
          if (inc0 && rr0 < mrank) { mrank = rr0; mvid = x0; }
          if (inc1 && rr1 < mrank) { mrank = rr1; mvid = x1; }
          if (inc2 && rr2 < mrank) { mrank = rr2; mvid = x2; }
          if (inc3 && rr3 < mrank) { mrank = rr3; mvid = x3; }
          u0 = inc0 && (x0 != mvid);
          u1 = inc1 && (x1 != mvid) && !(inc0 && x1 == x0);
          u2 = inc2 && (x2 != mvid) && !(inc0 && x2 == x0) && !(inc1 && x2 == x1);
          u3 = inc3 && (x3 != mvid) && !(inc0 && x3 == x0) && !(inc1 && x3 == x1) && !(inc2 && x3 == x2);
          uv = (mvid != vid);
          if (u0) atomicMin(&claim[x0], (unsigned)lane);
          if (u1) atomicMin(&claim[x1], (unsigned)lane);
          if (u2) atomicMin(&claim[x2], (unsigned)lane);
          if (u3) atomicMin(&claim[x3], (unsigned)lane);
          if (uv) atomicMin(&claim[vid], (unsigned)lane);
        }
        asm volatile("s_waitcnt lgkmcnt(0)" ::: "memory");
        bool win = !committed;
        if (!committed) {
          if (u0 && claim[x0] != (unsigned)lane) win = false;
          if (u1 && claim[x1] != (unsigned)lane) win = false;
          if (u2 && claim[x2] != (unsigned)lane) win = false;
          if (u3 && claim[x3] != (unsigned)lane) win = false;
          if (uv && claim[vid] != (unsigned)lane) win = false;
        }
        if (win) {
          if (u0) { const float p = vt - keyToFloat(Ka[rr0]);
                    if (p > 0.0f) { T += (double)p; S += (double)(p * logf(p)); }
                    parU[x0] = (unsigned short)mvid; }
          if (u1) { const float p = vt - keyToFloat(Ka[rr1]);
                    if (p > 0.0f) { T += (double)p; S += (double)(p * logf(p)); }
                    parU[x1] = (unsigned short)mvid; }
          if (u2) { const float p = vt - keyToFloat(Ka[rr2]);
                    if (p > 0.0f) { T += (double)p; S += (double)(p * logf(p)); }
                    parU[x2] = (unsigned short)mvid; }
          if (u3) { const float p = vt - keyToFloat(Ka[rr3]);
                    if (p > 0.0f) { T += (double)p; S += (double)(p * logf(p)); }
                    parU[x3] = (unsigned short)mvid; }
          if (uv) parU[vid] = (unsigned short)mvid;
          committed = true;
        }
        if (u0) claim[x0] = 0xFFFFFFFFu;
        if (u1) claim[x1] = 0xFFFFFFFFu;
        if (u2) claim[x2] = 0xFFFFFFFFu;
        if (u3) claim[x3] = 0xFFFFFFFFu;
        if (uv) claim[vid] = 0xFFFFFFFFu;
        asm volatile("s_waitcnt lgkmcnt(0)" ::: "memory");
      }
    }
    #pragma unroll
    for (int off = 32; off > 0; off >>= 1) {
      T += __shfl_down(T, off, 64);
      S += __shfl_down(S, off, 64);
    }
    if (lane == 0)
      out[blockIdx.x] = (T > 0.0) ? (float)(log(T) - S / T) : 0.0f;
  }
}

extern "C" void kernel_launch(void* const* d_in, const int* in_sizes, int n_in,
                              void* d_out, int out_size, void* d_ws, size_t ws_size,
                              hipStream_t stream) {
  (void)n_in; (void)out_size; (void)d_ws; (void)ws_size;
  const float* x = (const float*)d_in[0];
  float* out = (float*)d_out;
  int n_img = in_sizes[0] / NV;   // 64
  if (n_img <= 0) n_img = 1;
  topo_pk<<<n_img, NT, 0, stream>>>(x, out);
}

// Round 20
// 555.950 us; speedup vs baseline: 5.2777x; 1.0057x over previous
//
#include <hip/hip_runtime.h>

#define H_ 96
#define W_ 96
#define NV (H_ * W_)      // 9216 = 16 waves * 576
#define NT 1024
#define WELEM 576         // elements per wave
#define NSUB 9            // sub-rounds of 64 per wave

// arena layout (bytes):
//  Ka    @ 0       u32[9216]   (36864)
//  Kb    @ 36864   u32[9216]   (36864) -> reused as claim (u32[9216]) in P4
//  Pa    @ 73728   u16[9216]   (18432)
//  Pb    @ 92160   u16[9216]   (18432) -> reused as parU in P4
//  hist  @ 110592  u32[16*256] (16384)
//  total 126976 B (+128 B scan scratch) <= 160 KiB
#define ARENA_BYTES 126976

__device__ __forceinline__ float keyToFloat(unsigned int k) {
  return __uint_as_float((k & 0x80000000u) ? (k ^ 0x80000000u) : ~k);
}
__device__ __forceinline__ unsigned int bitsToKey(unsigned int b) {
  return b ^ ((b & 0x80000000u) ? 0xFFFFFFFFu : 0x80000000u);
}

__global__ __launch_bounds__(NT, 1)
void topo_pk(const float* __restrict__ x, float* __restrict__ out) {
  __shared__ unsigned int arenaW[ARENA_BYTES / 4];
  __shared__ unsigned int waveS[16];
  __shared__ unsigned int waveB[16];
  unsigned char* arena = (unsigned char*)arenaW;
  unsigned int*   Ka    = (unsigned int*)(arena);
  unsigned int*   Kb    = (unsigned int*)(arena + 36864);
  unsigned short* Pa    = (unsigned short*)(arena + 73728);
  unsigned short* Pb    = (unsigned short*)(arena + 92160);
  unsigned int*   hist  = (unsigned int*)(arena + 110592);
  unsigned short* parU  = (unsigned short*)(arena + 92160);   // P4 (Pb dead)
  unsigned int*   claim = (unsigned int*)(arena + 36864);     // P4 (Kb dead)

  const int tid = threadIdx.x;
  const int wv = tid >> 6, ln = tid & 63;
  const float* img = x + (size_t)blockIdx.x * NV;

  // ---- P1: order-preserving keys + identity payload ----
  for (int i = tid; i < NV; i += NT) {
    Ka[i] = bitsToKey(__float_as_uint(img[i]));
    Pa[i] = (unsigned short)i;
  }
  __syncthreads();

  // ---- P2: 4-pass 8-bit LSD radix sort (stable via ballot multi-split) ----
  const int wbase = wv * WELEM;
  for (int pass = 0; pass < 4; ++pass) {
    const unsigned int*   Ks = (pass & 1) ? Kb : Ka;
    const unsigned short* Ps = (pass & 1) ? Pb : Pa;
    unsigned int*   Kd = (pass & 1) ? Ka : Kb;
    unsigned short* Pd = (pass & 1) ? Pa : Pb;
    const int sh = pass << 3;

    // zero per-wave histograms
    for (int i = tid; i < 16 * 256; i += NT) hist[i] = 0u;
    __syncthreads();

    // count: per-wave running digit counts; rank-in-wave via ballot multi-split
    unsigned kreg[NSUB];
    unsigned rk[NSUB];     // (digit << 16) | rank_in_wave
    #pragma unroll
    for (int j = 0; j < NSUB; ++j) {
      const unsigned k = Ks[wbase + j * 64 + ln];
      kreg[j] = k;
      const unsigned d = (k >> sh) & 255u;
      unsigned long long mask = ~0ull;
      #pragma unroll
      for (int b = 0; b < 8; ++b) {
        const unsigned long long bb = __ballot((d >> b) & 1u);
        mask &= ((d >> b) & 1u) ? bb : ~bb;
      }
      const unsigned long long below = mask & ((1ull << ln) - 1ull);
      const unsigned old = hist[wv * 256 + d];           // broadcast per group
      rk[j] = (d << 16) | (old + (unsigned)__popcll(below));
      if (below == 0ull)                                 // group leader bumps count
        hist[wv * 256 + d] = old + (unsigned)__popcll(mask);
    }
    __syncthreads();

    // exclusive scan over seq s = d*16 + w  (digit-major, then wave -> stable)
    {
      unsigned v0, v1, v2, v3;
      const int s0 = tid * 4;
      v0 = hist[((s0 + 0) & 15) * 256 + ((s0 + 0) >> 4)];
      v1 = hist[((s0 + 1) & 15) * 256 + ((s0 + 1) >> 4)];
      v2 = hist[((s0 + 2) & 15) * 256 + ((s0 + 2) >> 4)];
      v3 = hist[((s0 + 3) & 15) * 256 + ((s0 + 3) >> 4)];
      const unsigned ts = v0 + v1 + v2 + v3;
      unsigned incl = ts;
      #pragma unroll
      for (int off = 1; off < 64; off <<= 1) {
        const unsigned n = (unsigned)__shfl_up((int)incl, off, 64);
        if (ln >= off) incl += n;
      }
      if (ln == 63) waveS[wv] = incl;
      __syncthreads();
      if (tid < 16) {
        unsigned s = 0;
        for (int q = 0; q < 16; ++q) { if (q == tid) break; s += waveS[q]; }
        waveB[tid] = s;
      }
      __syncthreads();
      unsigned run = waveB[wv] + (incl - ts);
      hist[((s0 + 0) & 15) * 256 + ((s0 + 0) >> 4)] = run; run += v0;
      hist[((s0 + 1) & 15) * 256 + ((s0 + 1) >> 4)] = run; run += v1;
      hist[((s0 + 2) & 15) * 256 + ((s0 + 2) >> 4)] = run; run += v2;
      hist[((s0 + 3) & 15) * 256 + ((s0 + 3) >> 4)] = run;
    }
    __syncthreads();

    // scatter: dest = scannedBase[(d, wv)] + rank_in_wave
    #pragma unroll
    for (int j = 0; j < NSUB; ++j) {
      const int e = wbase + j * 64 + ln;
      const unsigned d = rk[j] >> 16;
      const unsigned dest = hist[wv * 256 + d] + (rk[j] & 0xFFFFu);
      Kd[dest] = kreg[j];
      Pd[dest] = Ps[e];
    }
    __syncthreads();
  }
  // after 4 passes data is back in Ka / Pa

  // ---- P3: UF init + claim init ----
  for (int t = tid; t < NV; t += NT) parU[Pa[t]] = (unsigned short)(0x8000u | (unsigned)t);
  for (int i = tid; i < NV; i += NT) claim[i] = 0xFFFFFFFFu;
  __syncthreads();

  // ---- P4: wave-0 parallel-commit Kruskal over ranks (verbatim from R18) ----
  if (tid < 64) {
    const int lane = tid;
    double T = 0.0, S = 0.0;
    for (int ch = 0; ch < NV / 64; ++ch) {
      const int t = ch * 64 + lane;
      const int vid = (int)Pa[t];
      const unsigned keyT = Ka[t];
      const float vt = keyToFloat(keyT);
      const int r = vid / W_, c = vid - r * W_;
      const int nv0 = vid - 1, nv1 = vid + 1, nv2 = vid - W_, nv3 = vid + W_;
      const bool bb0 = (c > 0), bb1 = (c < W_ - 1), bb2 = (r > 0), bb3 = (r < H_ - 1);
      const unsigned kk0 = bb0 ? bitsToKey(__float_as_uint(img[nv0])) : 0xFFFFFFFFu;
      const unsigned kk1 = bb1 ? bitsToKey(__float_as_uint(img[nv1])) : 0xFFFFFFFFu;
      const unsigned kk2 = bb2 ? bitsToKey(__float_as_uint(img[nv2])) : 0xFFFFFFFFu;
      const unsigned kk3 = bb3 ? bitsToKey(__float_as_uint(img[nv3])) : 0xFFFFFFFFu;
      const bool inc0 = bb0 && (kk0 <= keyT);
      const bool inc1 = bb1 && (kk1 <= keyT);
      const bool inc2 = bb2 && (kk2 <= keyT);
      const bool inc3 = bb3 && (kk3 <= keyT);
      int x0 = inc0 ? nv0 : vid, x1 = inc1 ? nv1 : vid;
      int x2 = inc2 ? nv2 : vid, x3 = inc3 ? nv3 : vid;
      unsigned e0 = 0, e1 = 0, e2 = 0, e3 = 0;
      bool committed = false;

      for (;;) {
        if (__ballot(!committed) == 0ull) break;
        if (!committed) {
          bool d0 = !inc0, d1 = !inc1, d2 = !inc2, d3 = !inc3;
          while (!(d0 && d1 && d2 && d3)) {
            if (!d0) { unsigned e = parU[x0]; if (e & 0x8000u) { e0 = e; d0 = true; } else x0 = (int)e; }
            if (!d1) { unsigned e = parU[x1]; if (e & 0x8000u) { e1 = e; d1 = true; } else x1 = (int)e; }
            if (!d2) { unsigned e = parU[x2]; if (e & 0x8000u) { e2 = e; d2 = true; } else x2 = (int)e; }
            if (!d3) { unsigned e = parU[x3]; if (e & 0x8000u) { e3 = e; d3 = true; } else x3 = (int)e; }
          }
          if (inc0 && nv0 != x0) parU[nv0] = (unsigned short)x0;
          if (inc1 && nv1 != x1) parU[nv1] = (unsigned short)x1;
          if (inc2 && nv2 != x2) parU[nv2] = (unsigned short)x2;
          if (inc3 && nv3 != x3) parU[nv3] = (unsigned short)x3;
        }
        bool u0 = false, u1 = false, u2 = false, u3 = false, uv = false;
        int mvid = vid, mrank = t;
        int rr0 = 0, rr1 = 0, rr2 = 0, rr3 = 0;
        if (!committed) {
          rr0 = (int)(e0 & 0x3FFFu); rr1 = (int)(e1 & 0x3FFFu);
          rr2 = (int)(e2 & 0x3FFFu); rr3 = (int)(e3 & 0x3FFFu);
          if (inc0 && rr0 < mrank) { mrank = rr0; mvid = x0; }
          if (inc1 && rr1 < mrank) { mrank = rr1; mvid = x1; }
          if (inc2 && rr2 < mrank) { mrank = rr2; mvid = x2; }
          if (inc3 && rr3 < mrank) { mrank = rr3; mvid = x3; }
          u0 = inc0 && (x0 != mvid);
          u1 = inc1 && (x1 != mvid) && !(inc0 && x1 == x0);
          u2 = inc2 && (x2 != mvid) && !(inc0 && x2 == x0) && !(inc1 && x2 == x1);
          u3 = inc3 && (x3 != mvid) && !(inc0 && x3 == x0) && !(inc1 && x3 == x1) && !(inc2 && x3 == x2);
          uv = (mvid != vid);
          if (u0) atomicMin(&claim[x0], (unsigned)lane);
          if (u1) atomicMin(&claim[x1], (unsigned)lane);
          if (u2) atomicMin(&claim[x2], (unsigned)lane);
          if (u3) atomicMin(&claim[x3], (unsigned)lane);
          if (uv) atomicMin(&claim[vid], (unsigned)lane);
        }
        asm volatile("s_waitcnt lgkmcnt(0)" ::: "memory");
        bool win = !committed;
        if (!committed) {
          if (u0 && claim[x0] != (unsigned)lane) win = false;
          if (u1 && claim[x1] != (unsigned)lane) win = false;
          if (u2 && claim[x2] != (unsigned)lane) win = false;
          if (u3 && claim[x3] != (unsigned)lane) win = false;
          if (uv && claim[vid] != (unsigned)lane) win = false;
        }
        if (win) {
          if (u0) { const float p = vt - keyToFloat(Ka[rr0]);
                    if (p > 0.0f) { T += (double)p; S += (double)(p * logf(p)); }
                    parU[x0] = (unsigned short)mvid; }
          if (u1) { const float p = vt - keyToFloat(Ka[rr1]);
                    if (p > 0.0f) { T += (double)p; S += (double)(p * logf(p)); }
                    parU[x1] = (unsigned short)mvid; }
          if (u2) { const float p = vt - keyToFloat(Ka[rr2]);
                    if (p > 0.0f) { T += (double)p; S += (double)(p * logf(p)); }
                    parU[x2] = (unsigned short)mvid; }
          if (u3) { const float p = vt - keyToFloat(Ka[rr3]);
                    if (p > 0.0f) { T += (double)p; S += (double)(p * logf(p)); }
                    parU[x3] = (unsigned short)mvid; }
          if (uv) parU[vid] = (unsigned short)mvid;
          committed = true;
        }
        if (u0) claim[x0] = 0xFFFFFFFFu;
        if (u1) claim[x1] = 0xFFFFFFFFu;
        if (u2) claim[x2] = 0xFFFFFFFFu;
        if (u3) claim[x3] = 0xFFFFFFFFu;
        if (uv) claim[vid] = 0xFFFFFFFFu;
        asm volatile("s_waitcnt lgkmcnt(0)" ::: "memory");
      }
    }
    #pragma unroll
    for (int off = 32; off > 0; off >>= 1) {
      T += __shfl_down(T, off, 64);
      S += __shfl_down(S, off, 64);
    }
    if (lane == 0)
      out[blockIdx.x] = (T > 0.0) ? (float)(log(T) - S / T) : 0.0f;
  }
}

extern "C" void kernel_launch(void* const* d_in, const int* in_sizes, int n_in,
                              void* d_out, int out_size, void* d_ws, size_t ws_size,
                              hipStream_t stream) {
  (void)n_in; (void)out_size; (void)d_ws; (void)ws_size;
  const float* x = (const float*)d_in[0];
  float* out = (float*)d_out;
  int n_img = in_sizes[0] / NV;   // 64
  if (n_img <= 0) n_img = 1;
  topo_pk<<<n_img, NT, 0, stream>>>(x, out);
}

// Round 21
// 154.909 us; speedup vs baseline: 18.9410x; 3.5889x over previous
//
#include <hip/hip_runtime.h>

#define H_ 96
#define W_ 96
#define NV (H_ * W_)      // 9216 = 16 waves * 576 = 9 * 1024
#define NT 1024
#define WELEM 576         // sort: elements per wave
#define NSUB 9            // sort: sub-rounds of 64 per wave

// arena layout (bytes):
//  Ka    @ 0       u32[9216]   (36864)
//  Kb    @ 36864   u32[9216]   (36864) -> reused as claim (u32[9216]) in P4
//  Pa    @ 73728   u16[9216]   (18432)
//  Pb    @ 92160   u16[9216]   (18432) -> reused as parU in P4
//  hist  @ 110592  u32[16*256] (16384)
//  total 126976 B <= 160 KiB
#define ARENA_BYTES 126976

__device__ __forceinline__ float keyToFloat(unsigned int k) {
  return __uint_as_float((k & 0x80000000u) ? (k ^ 0x80000000u) : ~k);
}
__device__ __forceinline__ unsigned int bitsToKey(unsigned int b) {
  return b ^ ((b & 0x80000000u) ? 0xFFFFFFFFu : 0x80000000u);
}

__global__ __launch_bounds__(NT, 1)
void topo_pk(const float* __restrict__ x, float* __restrict__ out) {
  __shared__ unsigned int arenaW[ARENA_BYTES / 4];
  __shared__ unsigned int waveS[16];
  __shared__ unsigned int waveB[16];
  __shared__ double Td[16], Sd[16];
  unsigned char* arena = (unsigned char*)arenaW;
  unsigned int*   Ka    = (unsigned int*)(arena);
  unsigned int*   Kb    = (unsigned int*)(arena + 36864);
  unsigned short* Pa    = (unsigned short*)(arena + 73728);
  unsigned short* Pb    = (unsigned short*)(arena + 92160);
  unsigned int*   hist  = (unsigned int*)(arena + 110592);
  unsigned short* parU  = (unsigned short*)(arena + 92160);   // P4 (Pb dead)
  unsigned int*   claim = (unsigned int*)(arena + 36864);     // P4 (Kb dead)

  const int tid = threadIdx.x;
  const int wv = tid >> 6, ln = tid & 63;
  const float* img = x + (size_t)blockIdx.x * NV;

  // ---- P1: order-preserving keys + identity payload ----
  for (int i = tid; i < NV; i += NT) {
    Ka[i] = bitsToKey(__float_as_uint(img[i]));
    Pa[i] = (unsigned short)i;
  }
  __syncthreads();

  // ---- P2: 4-pass 8-bit LSD radix sort (stable via ballot multi-split) ----
  const int wbase = wv * WELEM;
  for (int pass = 0; pass < 4; ++pass) {
    const unsigned int*   Ks = (pass & 1) ? Kb : Ka;
    const unsigned short* Ps = (pass & 1) ? Pb : Pa;
    unsigned int*   Kd = (pass & 1) ? Ka : Kb;
    unsigned short* Pd = (pass & 1) ? Pa : Pb;
    const int sh = pass << 3;

    for (int i = tid; i < 16 * 256; i += NT) hist[i] = 0u;
    __syncthreads();

    unsigned kreg[NSUB];
    unsigned rk[NSUB];     // (digit << 16) | rank_in_wave
    #pragma unroll
    for (int j = 0; j < NSUB; ++j) {
      const unsigned k = Ks[wbase + j * 64 + ln];
      kreg[j] = k;
      const unsigned d = (k >> sh) & 255u;
      unsigned long long mask = ~0ull;
      #pragma unroll
      for (int b = 0; b < 8; ++b) {
        const unsigned long long bb = __ballot((d >> b) & 1u);
        mask &= ((d >> b) & 1u) ? bb : ~bb;
      }
      const unsigned long long below = mask & ((1ull << ln) - 1ull);
      const unsigned old = hist[wv * 256 + d];
      rk[j] = (d << 16) | (old + (unsigned)__popcll(below));
      if (below == 0ull)
        hist[wv * 256 + d] = old + (unsigned)__popcll(mask);
    }
    __syncthreads();

    // exclusive scan over seq s = d*16 + w (digit-major, then wave -> stable)
    {
      unsigned v0, v1, v2, v3;
      const int s0 = tid * 4;
      v0 = hist[((s0 + 0) & 15) * 256 + ((s0 + 0) >> 4)];
      v1 = hist[((s0 + 1) & 15) * 256 + ((s0 + 1) >> 4)];
      v2 = hist[((s0 + 2) & 15) * 256 + ((s0 + 2) >> 4)];
      v3 = hist[((s0 + 3) & 15) * 256 + ((s0 + 3) >> 4)];
      const unsigned ts = v0 + v1 + v2 + v3;
      unsigned incl = ts;
      #pragma unroll
      for (int off = 1; off < 64; off <<= 1) {
        const unsigned n = (unsigned)__shfl_up((int)incl, off, 64);
        if (ln >= off) incl += n;
      }
      if (ln == 63) waveS[wv] = incl;
      __syncthreads();
      if (tid < 16) {
        unsigned s = 0;
        for (int q = 0; q < 16; ++q) { if (q == tid) break; s += waveS[q]; }
        waveB[tid] = s;
      }
      __syncthreads();
      unsigned run = waveB[wv] + (incl - ts);
      hist[((s0 + 0) & 15) * 256 + ((s0 + 0) >> 4)] = run; run += v0;
      hist[((s0 + 1) & 15) * 256 + ((s0 + 1) >> 4)] = run; run += v1;
      hist[((s0 + 2) & 15) * 256 + ((s0 + 2) >> 4)] = run; run += v2;
      hist[((s0 + 3) & 15) * 256 + ((s0 + 3) >> 4)] = run;
    }
    __syncthreads();

    #pragma unroll
    for (int j = 0; j < NSUB; ++j) {
      const int e = wbase + j * 64 + ln;
      const unsigned d = rk[j] >> 16;
      const unsigned dest = hist[wv * 256 + d] + (rk[j] & 0xFFFFu);
      Kd[dest] = kreg[j];
      Pd[dest] = Ps[e];
    }
    __syncthreads();
  }
  // after 4 passes data is back in Ka / Pa

  // ---- P3: UF init + claim init ----
  for (int t = tid; t < NV; t += NT) parU[Pa[t]] = (unsigned short)(0x8000u | (unsigned)t);
  for (int i = tid; i < NV; i += NT) claim[i] = 0xFFFFFFFFu;
  __syncthreads();

  // ---- P4: block-wide parallel-commit Kruskal (window = 1024 ranks) ----
  double T = 0.0, S = 0.0;
  for (int ch = 0; ch < NV / NT; ++ch) {          // 9 chunks
    const int t = ch * NT + tid;
    const int vid = (int)Pa[t];
    const unsigned keyT = Ka[t];
    const float vt = keyToFloat(keyT);
    const int r = vid / W_, c = vid - r * W_;
    const int nv0 = vid - 1, nv1 = vid + 1, nv2 = vid - W_, nv3 = vid + W_;
    const bool bb0 = (c > 0), bb1 = (c < W_ - 1), bb2 = (r > 0), bb3 = (r < H_ - 1);
    // inclusion by VALUE (immune to UF state); equal keys -> both sides process (2nd is a cycle)
    const unsigned kk0 = bb0 ? bitsToKey(__float_as_uint(img[nv0])) : 0xFFFFFFFFu;
    const unsigned kk1 = bb1 ? bitsToKey(__float_as_uint(img[nv1])) : 0xFFFFFFFFu;
    const unsigned kk2 = bb2 ? bitsToKey(__float_as_uint(img[nv2])) : 0xFFFFFFFFu;
    const unsigned kk3 = bb3 ? bitsToKey(__float_as_uint(img[nv3])) : 0xFFFFFFFFu;
    const bool inc0 = bb0 && (kk0 <= keyT);
    const bool inc1 = bb1 && (kk1 <= keyT);
    const bool inc2 = bb2 && (kk2 <= keyT);
    const bool inc3 = bb3 && (kk3 <= keyT);
    int x0 = inc0 ? nv0 : vid, x1 = inc1 ? nv1 : vid;
    int x2 = inc2 ? nv2 : vid, x3 = inc3 ? nv3 : vid;
    unsigned e0 = 0, e1 = 0, e2 = 0, e3 = 0;
    bool committed = false;

    for (;;) {
      // phase A: re-chase (uncommitted lanes; roots are stable in this phase)
      if (!committed) {
        bool d0 = !inc0, d1 = !inc1, d2 = !inc2, d3 = !inc3;
        while (!(d0 && d1 && d2 && d3)) {
          if (!d0) { unsigned e = parU[x0]; if (e & 0x8000u) { e0 = e; d0 = true; } else x0 = (int)e; }
          if (!d1) { unsigned e = parU[x1]; if (e & 0x8000u) { e1 = e; d1 = true; } else x1 = (int)e; }
          if (!d2) { unsigned e = parU[x2]; if (e & 0x8000u) { e2 = e; d2 = true; } else x2 = (int)e; }
          if (!d3) { unsigned e = parU[x3]; if (e & 0x8000u) { e3 = e; d3 = true; } else x3 = (int)e; }
        }
        // path compression (pointer-forwarding only; no root demotions this phase)
        if (inc0 && nv0 != x0) parU[nv0] = (unsigned short)x0;
        if (inc1 && nv1 != x1) parU[nv1] = (unsigned short)x1;
        if (inc2 && nv2 != x2) parU[nv2] = (unsigned short)x2;
        if (inc3 && nv3 != x3) parU[nv3] = (unsigned short)x3;
      }
      // phase B: survivor, dedupe, claims (claim value = tid == rank order in window)
      bool u0 = false, u1 = false, u2 = false, u3 = false, uv = false;
      int mvid = vid;
      int rr0 = 0, rr1 = 0, rr2 = 0, rr3 = 0;
      if (!committed) {
        int mrank = t;
        rr0 = (int)(e0 & 0x3FFFu); rr1 = (int)(e1 & 0x3FFFu);
        rr2 = (int)(e2 & 0x3FFFu); rr3 = (int)(e3 & 0x3FFFu);
        if (inc0 && rr0 < mrank) { mrank = rr0; mvid = x0; }
        if (inc1 && rr1 < mrank) { mrank = rr1; mvid = x1; }
        if (inc2 && rr2 < mrank) { mrank = rr2; mvid = x2; }
        if (inc3 && rr3 < mrank) { mrank = rr3; mvid = x3; }
        u0 = inc0 && (x0 != mvid);
        u1 = inc1 && (x1 != mvid) && !(inc0 && x1 == x0);
        u2 = inc2 && (x2 != mvid) && !(inc0 && x2 == x0) && !(inc1 && x2 == x1);
        u3 = inc3 && (x3 != mvid) && !(inc0 && x3 == x0) && !(inc1 && x3 == x1) && !(inc2 && x3 == x2);
        uv = (mvid != vid);
        if (u0) atomicMin(&claim[x0], (unsigned)tid);
        if (u1) atomicMin(&claim[x1], (unsigned)tid);
        if (u2) atomicMin(&claim[x2], (unsigned)tid);
        if (u3) atomicMin(&claim[x3], (unsigned)tid);
        if (uv) atomicMin(&claim[vid], (unsigned)tid);
      }
      __syncthreads();                      // claims visible
      // phase C: win check (own every slot you will write)
      bool win = !committed;
      if (!committed) {
        if (u0 && claim[x0] != (unsigned)tid) win = false;
        if (u1 && claim[x1] != (unsigned)tid) win = false;
        if (u2 && claim[x2] != (unsigned)tid) win = false;
        if (u3 && claim[x3] != (unsigned)tid) win = false;
        if (uv && claim[vid] != (unsigned)tid) win = false;
      }
      __syncthreads();                      // all checks read claims before resets
      // phase D: commit (winners; claimed slots exclusive) + reset claims (all claimants)
      if (win && !committed) {
        if (u0) { const float p = vt - keyToFloat(Ka[rr0]);
                  if (p > 0.0f) { T += (double)p; S += (double)(p * logf(p)); }
                  parU[x0] = (unsigned short)mvid; }
        if (u1) { const float p = vt - keyToFloat(Ka[rr1]);
                  if (p > 0.0f) { T += (double)p; S += (double)(p * logf(p)); }
                  parU[x1] = (unsigned short)mvid; }
        if (u2) { const float p = vt - keyToFloat(Ka[rr2]);
                  if (p > 0.0f) { T += (double)p; S += (double)(p * logf(p)); }
                  parU[x2] = (unsigned short)mvid; }
        if (u3) { const float p = vt - keyToFloat(Ka[rr3]);
                  if (p > 0.0f) { T += (double)p; S += (double)(p * logf(p)); }
                  parU[x3] = (unsigned short)mvid; }
        if (uv) parU[vid] = (unsigned short)mvid;
        committed = true;
      }
      if (u0) claim[x0] = 0xFFFFFFFFu;
      if (u1) claim[x1] = 0xFFFFFFFFu;
      if (u2) claim[x2] = 0xFFFFFFFFu;
      if (u3) claim[x3] = 0xFFFFFFFFu;
      if (uv) claim[vid] = 0xFFFFFFFFu;
      if (__syncthreads_count(!committed ? 1 : 0) == 0) break;  // commits/resets visible
    }
  }

  // ---- P5: block reduction of entropy accumulators ----
  #pragma unroll
  for (int off = 32; off > 0; off >>= 1) {
    T += __shfl_down(T, off, 64);
    S += __shfl_down(S, off, 64);
  }
  if (ln == 0) { Td[wv] = T; Sd[wv] = S; }
  __syncthreads();
  if (tid == 0) {
    double Tt = 0.0, St = 0.0;
    for (int q = 0; q < 16; ++q) { Tt += Td[q]; St += Sd[q]; }
    out[blockIdx.x] = (Tt > 0.0) ? (float)(log(Tt) - St / Tt) : 0.0f;
  }
}

extern "C" void kernel_launch(void* const* d_in, const int* in_sizes, int n_in,
                              void* d_out, int out_size, void* d_ws, size_t ws_size,
                              hipStream_t stream) {
  (void)n_in; (void)out_size; (void)d_ws; (void)ws_size;
  const float* x = (const float*)d_in[0];
  float* out = (float*)d_out;
  int n_img = in_sizes[0] / NV;   // 64
  if (n_img <= 0) n_img = 1;
  topo_pk<<<n_img, NT, 0, stream>>>(x, out);
}

// Round 22
// 148.719 us; speedup vs baseline: 19.7295x; 1.0416x over previous
//
#include <hip/hip_runtime.h>

#define H_ 96
#define W_ 96
#define NV (H_ * W_)      // 9216 = 16 waves * 576 = 9 * 1024
#define NT 1024
#define WELEM 576         // sort: elements per wave
#define NSUB 9            // sort: sub-rounds of 64 per wave

// arena layout (bytes):
//  Ka    @ 0       u32[9216]   (36864)
//  Kb    @ 36864   u32[9216]   (36864) -> reused as claim (u32[9216]) in P4
//  Pa    @ 73728   u16[9216]   (18432)
//  Pb    @ 92160   u16[9216]   (18432) -> reused as parU in P4
//  hist  @ 110592  u32[16*256] (16384)
//  total 126976 B <= 160 KiB
#define ARENA_BYTES 126976

__device__ __forceinline__ float keyToFloat(unsigned int k) {
  return __uint_as_float((k & 0x80000000u) ? (k ^ 0x80000000u) : ~k);
}
__device__ __forceinline__ unsigned int bitsToKey(unsigned int b) {
  return b ^ ((b & 0x80000000u) ? 0xFFFFFFFFu : 0x80000000u);
}

__global__ __launch_bounds__(NT, 1)
void topo_pk(const float* __restrict__ x, float* __restrict__ out) {
  __shared__ unsigned int arenaW[ARENA_BYTES / 4];
  __shared__ unsigned int waveS[16];
  __shared__ unsigned int waveB[16];
  __shared__ double Td[16], Sd[16];
  unsigned char* arena = (unsigned char*)arenaW;
  unsigned int*   Ka    = (unsigned int*)(arena);
  unsigned int*   Kb    = (unsigned int*)(arena + 36864);
  unsigned short* Pa    = (unsigned short*)(arena + 73728);
  unsigned short* Pb    = (unsigned short*)(arena + 92160);
  unsigned int*   hist  = (unsigned int*)(arena + 110592);
  unsigned short* parU  = (unsigned short*)(arena + 92160);   // P4 (Pb dead)
  unsigned int*   claim = (unsigned int*)(arena + 36864);     // P4 (Kb dead)

  const int tid = threadIdx.x;
  const int wv = tid >> 6, ln = tid & 63;
  const float* img = x + (size_t)blockIdx.x * NV;

  // ---- P2: 4-pass 8-bit LSD radix sort (stable via ballot multi-split);
  //      pass 0 reads img directly (P1 fused) ----
  const int wbase = wv * WELEM;
  for (int pass = 0; pass < 4; ++pass) {
    const unsigned int*   Ks = (pass & 1) ? Kb : Ka;
    const unsigned short* Ps = (pass & 1) ? Pb : Pa;
    unsigned int*   Kd = (pass & 1) ? Ka : Kb;
    unsigned short* Pd = (pass & 1) ? Pa : Pb;
    const int sh = pass << 3;

    for (int i = tid; i < 16 * 256; i += NT) hist[i] = 0u;
    __syncthreads();

    unsigned kreg[NSUB];
    unsigned rk[NSUB];     // (digit << 16) | rank_in_wave
    #pragma unroll
    for (int j = 0; j < NSUB; ++j) {
      const int e = wbase + j * 64 + ln;
      const unsigned k = (pass == 0) ? bitsToKey(__float_as_uint(img[e])) : Ks[e];
      kreg[j] = k;
      const unsigned d = (k >> sh) & 255u;
      unsigned long long mask = ~0ull;
      #pragma unroll
      for (int b = 0; b < 8; ++b) {
        const unsigned long long bb = __ballot((d >> b) & 1u);
        mask &= ((d >> b) & 1u) ? bb : ~bb;
      }
      const unsigned long long below = mask & ((1ull << ln) - 1ull);
      const unsigned old = hist[wv * 256 + d];
      rk[j] = (d << 16) | (old + (unsigned)__popcll(below));
      if (below == 0ull)
        hist[wv * 256 + d] = old + (unsigned)__popcll(mask);
    }
    __syncthreads();

    // exclusive scan over seq s = d*16 + w (digit-major, then wave -> stable)
    {
      unsigned v0, v1, v2, v3;
      const int s0 = tid * 4;
      v0 = hist[((s0 + 0) & 15) * 256 + ((s0 + 0) >> 4)];
      v1 = hist[((s0 + 1) & 15) * 256 + ((s0 + 1) >> 4)];
      v2 = hist[((s0 + 2) & 15) * 256 + ((s0 + 2) >> 4)];
      v3 = hist[((s0 + 3) & 15) * 256 + ((s0 + 3) >> 4)];
      const unsigned ts = v0 + v1 + v2 + v3;
      unsigned incl = ts;
      #pragma unroll
      for (int off = 1; off < 64; off <<= 1) {
        const unsigned n = (unsigned)__shfl_up((int)incl, off, 64);
        if (ln >= off) incl += n;
      }
      if (ln == 63) waveS[wv] = incl;
      __syncthreads();
      if (tid < 16) {
        unsigned s = 0;
        for (int q = 0; q < 16; ++q) { if (q == tid) break; s += waveS[q]; }
        waveB[tid] = s;
      }
      __syncthreads();
      unsigned run = waveB[wv] + (incl - ts);
      hist[((s0 + 0) & 15) * 256 + ((s0 + 0) >> 4)] = run; run += v0;
      hist[((s0 + 1) & 15) * 256 + ((s0 + 1) >> 4)] = run; run += v1;
      hist[((s0 + 2) & 15) * 256 + ((s0 + 2) >> 4)] = run; run += v2;
      hist[((s0 + 3) & 15) * 256 + ((s0 + 3) >> 4)] = run;
    }
    __syncthreads();

    #pragma unroll
    for (int j = 0; j < NSUB; ++j) {
      const int e = wbase + j * 64 + ln;
      const unsigned d = rk[j] >> 16;
      const unsigned dest = hist[wv * 256 + d] + (rk[j] & 0xFFFFu);
      Kd[dest] = kreg[j];
      Pd[dest] = (pass == 0) ? (unsigned short)e : Ps[e];
    }
    __syncthreads();
  }
  // after 4 passes data is back in Ka / Pa

  // ---- P3: UF init + claim init (claims init-once; epoch protocol needs no resets) ----
  for (int t = tid; t < NV; t += NT) parU[Pa[t]] = (unsigned short)(0x8000u | (unsigned)t);
  for (int i = tid; i < NV; i += NT) claim[i] = 0xFFFFFFFFu;
  __syncthreads();

  // ---- P4: block-wide parallel-commit Kruskal, epoch claims (2 barriers/round) ----
  double T = 0.0, S = 0.0;
  unsigned gr = 0;                                // global round counter (uniform)
  for (int ch = 0; ch < NV / NT; ++ch) {          // 9 chunks
    const int t = ch * NT + tid;
    const int vid = (int)Pa[t];
    const unsigned keyT = Ka[t];
    const float vt = keyToFloat(keyT);
    const int r = vid / W_, c = vid - r * W_;
    const int nv0 = vid - 1, nv1 = vid + 1, nv2 = vid - W_, nv3 = vid + W_;
    const bool bb0 = (c > 0), bb1 = (c < W_ - 1), bb2 = (r > 0), bb3 = (r < H_ - 1);
    // inclusion by VALUE (immune to UF state); equal keys -> both sides process (2nd is a cycle)
    const unsigned kk0 = bb0 ? bitsToKey(__float_as_uint(img[nv0])) : 0xFFFFFFFFu;
    const unsigned kk1 = bb1 ? bitsToKey(__float_as_uint(img[nv1])) : 0xFFFFFFFFu;
    const unsigned kk2 = bb2 ? bitsToKey(__float_as_uint(img[nv2])) : 0xFFFFFFFFu;
    const unsigned kk3 = bb3 ? bitsToKey(__float_as_uint(img[nv3])) : 0xFFFFFFFFu;
    const bool inc0 = bb0 && (kk0 <= keyT);
    const bool inc1 = bb1 && (kk1 <= keyT);
    const bool inc2 = bb2 && (kk2 <= keyT);
    const bool inc3 = bb3 && (kk3 <= keyT);
    int x0 = inc0 ? nv0 : vid, x1 = inc1 ? nv1 : vid;
    int x2 = inc2 ? nv2 : vid, x3 = inc3 ? nv3 : vid;
    unsigned e0 = 0, e1 = 0, e2 = 0, e3 = 0;
    bool committed = false;

    for (;;) {
      const unsigned cval = ((0x000FFFFFu - gr) << 10) | (unsigned)tid;
      ++gr;                                        // uniform across block
      // phase A: re-chase (uncommitted lanes; roots stable in this phase)
      if (!committed) {
        bool d0 = !inc0, d1 = !inc1, d2 = !inc2, d3 = !inc3;
        while (!(d0 && d1 && d2 && d3)) {
          if (!d0) { unsigned e = parU[x0]; if (e & 0x8000u) { e0 = e; d0 = true; } else x0 = (int)e; }
          if (!d1) { unsigned e = parU[x1]; if (e & 0x8000u) { e1 = e; d1 = true; } else x1 = (int)e; }
          if (!d2) { unsigned e = parU[x2]; if (e & 0x8000u) { e2 = e; d2 = true; } else x2 = (int)e; }
          if (!d3) { unsigned e = parU[x3]; if (e & 0x8000u) { e3 = e; d3 = true; } else x3 = (int)e; }
        }
        // path compression (pointer forwarding only; no demotions this phase)
        if (inc0 && nv0 != x0) parU[nv0] = (unsigned short)x0;
        if (inc1 && nv1 != x1) parU[nv1] = (unsigned short)x1;
        if (inc2 && nv2 != x2) parU[nv2] = (unsigned short)x2;
        if (inc3 && nv3 != x3) parU[nv3] = (unsigned short)x3;
      }
      // phase B: survivor, dedupe, claims (epoch value: later rounds always smaller)
      bool u0 = false, u1 = false, u2 = false, u3 = false, uv = false;
      int mvid = vid;
      int rr0 = 0, rr1 = 0, rr2 = 0, rr3 = 0;
      if (!committed) {
        int mrank = t;
        rr0 = (int)(e0 & 0x3FFFu); rr1 = (int)(e1 & 0x3FFFu);
        rr2 = (int)(e2 & 0x3FFFu); rr3 = (int)(e3 & 0x3FFFu);
        if (inc0 && rr0 < mrank) { mrank = rr0; mvid = x0; }
        if (inc1 && rr1 < mrank) { mrank = rr1; mvid = x1; }
        if (inc2 && rr2 < mrank) { mrank = rr2; mvid = x2; }
        if (inc3 && rr3 < mrank) { mrank = rr3; mvid = x3; }
        u0 = inc0 && (x0 != mvid);
        u1 = inc1 && (x1 != mvid) && !(inc0 && x1 == x0);
        u2 = inc2 && (x2 != mvid) && !(inc0 && x2 == x0) && !(inc1 && x2 == x1);
        u3 = inc3 && (x3 != mvid) && !(inc0 && x3 == x0) && !(inc1 && x3 == x1) && !(inc2 && x3 == x2);
        uv = (mvid != vid);
        if (u0) atomicMin(&claim[x0], cval);
        if (u1) atomicMin(&claim[x1], cval);
        if (u2) atomicMin(&claim[x2], cval);
        if (u3) atomicMin(&claim[x3], cval);
        if (uv) atomicMin(&claim[vid], cval);
      }
      __syncthreads();                      // claims visible
      // phase C: win check + commit (claim[] read-only now; parU/K disjoint)
      if (!committed) {
        bool win = true;
        if (u0 && claim[x0] != cval) win = false;
        if (u1 && claim[x1] != cval) win = false;
        if (u2 && claim[x2] != cval) win = false;
        if (u3 && claim[x3] != cval) win = false;
        if (uv && claim[vid] != cval) win = false;
        if (win) {
          if (u0) { const float p = vt - keyToFloat(Ka[rr0]);
                    if (p > 0.0f) { T += (double)p; S += (double)(p * logf(p)); }
                    parU[x0] = (unsigned short)mvid; }
          if (u1) { const float p = vt - keyToFloat(Ka[rr1]);
                    if (p > 0.0f) { T += (double)p; S += (double)(p * logf(p)); }
                    parU[x1] = (unsigned short)mvid; }
          if (u2) { const float p = vt - keyToFloat(Ka[rr2]);
                    if (p > 0.0f) { T += (double)p; S += (double)(p * logf(p)); }
                    parU[x2] = (unsigned short)mvid; }
          if (u3) { const float p = vt - keyToFloat(Ka[rr3]);
                    if (p > 0.0f) { T += (double)p; S += (double)(p * logf(p)); }
                    parU[x3] = (unsigned short)mvid; }
          if (uv) parU[vid] = (unsigned short)mvid;
          committed = true;
        }
      }
      if (__syncthreads_count(!committed ? 1 : 0) == 0) break;  // commits visible
    }
  }

  // ---- P5: block reduction of entropy accumulators ----
  #pragma unroll
  for (int off = 32; off > 0; off >>= 1) {
    T += __shfl_down(T, off, 64);
    S += __shfl_down(S, off, 64);
  }
  if (ln == 0) { Td[wv] = T; Sd[wv] = S; }
  __syncthreads();
  if (tid == 0) {
    double Tt = 0.0, St = 0.0;
    for (int q = 0; q < 16; ++q) { Tt += Td[q]; St += Sd[q]; }
    out[blockIdx.x] = (Tt > 0.0) ? (float)(log(Tt) - St / Tt) : 0.0f;
  }
}

extern "C" void kernel_launch(void* const* d_in, const int* in_sizes, int n_in,
                              void* d_out, int out_size, void* d_ws, size_t ws_size,
                              hipStream_t stream) {
  (void)n_in; (void)out_size; (void)d_ws; (void)ws_size;
  const float* x = (const float*)d_in[0];
  float* out = (float*)d_out;
  int n_img = in_sizes[0] / NV;   // 64
  if (n_img <= 0) n_img = 1;
  topo_pk<<<n_img, NT, 0, stream>>>(x, out);
}

// Round 23
// 144.231 us; speedup vs baseline: 20.3433x; 1.0311x over previous
//
#include <hip/hip_runtime.h>

#define H_ 96
#define W_ 96
#define NV (H_ * W_)      // 9216 = 16 waves * 576 = 9 * 1024
#define NT 1024
#define WELEM 576         // sort: elements per wave
#define NSUB 9            // sort: sub-rounds of 64 per wave

// arena layout (bytes):
//  Ka    @ 0       u32[9216]   (36864)
//  Kb    @ 36864   u32[9216]   (36864) -> reused as claim (u32[9216]) in P4
//  Pa    @ 73728   u16[9216]   (18432)
//  Pb    @ 92160   u16[9216]   (18432) -> reused as parU in P4
//  hist  @ 110592  u32[16*256] (16384)
//  incB  @ 126976  u8[9216]    (9216)   4-neighbor inclusion bits per vid
//  total 136192 B <= 160 KiB
#define ARENA_BYTES 136192

__device__ __forceinline__ float keyToFloat(unsigned int k) {
  return __uint_as_float((k & 0x80000000u) ? (k ^ 0x80000000u) : ~k);
}
__device__ __forceinline__ unsigned int bitsToKey(unsigned int b) {
  return b ^ ((b & 0x80000000u) ? 0xFFFFFFFFu : 0x80000000u);
}

__global__ __launch_bounds__(NT, 1)
void topo_pk(const float* __restrict__ x, float* __restrict__ out) {
  __shared__ unsigned int arenaW[ARENA_BYTES / 4];
  __shared__ unsigned int waveS[16];
  __shared__ unsigned int waveB[16];
  __shared__ double Td[16], Sd[16];
  unsigned char* arena = (unsigned char*)arenaW;
  unsigned int*   Ka    = (unsigned int*)(arena);
  unsigned int*   Kb    = (unsigned int*)(arena + 36864);
  unsigned short* Pa    = (unsigned short*)(arena + 73728);
  unsigned short* Pb    = (unsigned short*)(arena + 92160);
  unsigned int*   hist  = (unsigned int*)(arena + 110592);
  unsigned char*  incB  = (unsigned char*)(arena + 126976);
  unsigned short* parU  = (unsigned short*)(arena + 92160);   // P4 (Pb dead)
  unsigned int*   claim = (unsigned int*)(arena + 36864);     // P4 (Kb dead)

  const int tid = threadIdx.x;
  const int wv = tid >> 6, ln = tid & 63;
  const float* img = x + (size_t)blockIdx.x * NV;

  // ---- P2: 4-pass 8-bit LSD radix sort (stable via ballot multi-split);
  //      pass 0 reads img directly (P1 fused) ----
  const int wbase = wv * WELEM;
  for (int pass = 0; pass < 4; ++pass) {
    const unsigned int*   Ks = (pass & 1) ? Kb : Ka;
    const unsigned short* Ps = (pass & 1) ? Pb : Pa;
    unsigned int*   Kd = (pass & 1) ? Ka : Kb;
    unsigned short* Pd = (pass & 1) ? Pa : Pb;
    const int sh = pass << 3;

    for (int i = tid; i < 16 * 256; i += NT) hist[i] = 0u;
    __syncthreads();

    unsigned kreg[NSUB];
    unsigned rk[NSUB];     // (digit << 16) | rank_in_wave
    #pragma unroll
    for (int j = 0; j < NSUB; ++j) {
      const int e = wbase + j * 64 + ln;
      const unsigned k = (pass == 0) ? bitsToKey(__float_as_uint(img[e])) : Ks[e];
      kreg[j] = k;
      const unsigned d = (k >> sh) & 255u;
      unsigned long long mask = ~0ull;
      #pragma unroll
      for (int b = 0; b < 8; ++b) {
        const unsigned long long bb = __ballot((d >> b) & 1u);
        mask &= ((d >> b) & 1u) ? bb : ~bb;
      }
      const unsigned long long below = mask & ((1ull << ln) - 1ull);
      const unsigned old = hist[wv * 256 + d];
      rk[j] = (d << 16) | (old + (unsigned)__popcll(below));
      if (below == 0ull)
        hist[wv * 256 + d] = old + (unsigned)__popcll(mask);
    }
    __syncthreads();

    // exclusive scan over seq s = d*16 + w (digit-major, then wave -> stable)
    {
      unsigned v0, v1, v2, v3;
      const int s0 = tid * 4;
      v0 = hist[((s0 + 0) & 15) * 256 + ((s0 + 0) >> 4)];
      v1 = hist[((s0 + 1) & 15) * 256 + ((s0 + 1) >> 4)];
      v2 = hist[((s0 + 2) & 15) * 256 + ((s0 + 2) >> 4)];
      v3 = hist[((s0 + 3) & 15) * 256 + ((s0 + 3) >> 4)];
      const unsigned ts = v0 + v1 + v2 + v3;
      unsigned incl = ts;
      #pragma unroll
      for (int off = 1; off < 64; off <<= 1) {
        const unsigned n = (unsigned)__shfl_up((int)incl, off, 64);
        if (ln >= off) incl += n;
      }
      if (ln == 63) waveS[wv] = incl;
      __syncthreads();
      if (tid < 16) {
        unsigned s = 0;
        for (int q = 0; q < 16; ++q) { if (q == tid) break; s += waveS[q]; }
        waveB[tid] = s;
      }
      __syncthreads();
      unsigned run = waveB[wv] + (incl - ts);
      hist[((s0 + 0) & 15) * 256 + ((s0 + 0) >> 4)] = run; run += v0;
      hist[((s0 + 1) & 15) * 256 + ((s0 + 1) >> 4)] = run; run += v1;
      hist[((s0 + 2) & 15) * 256 + ((s0 + 2) >> 4)] = run; run += v2;
      hist[((s0 + 3) & 15) * 256 + ((s0 + 3) >> 4)] = run;
    }
    __syncthreads();

    #pragma unroll
    for (int j = 0; j < NSUB; ++j) {
      const int e = wbase + j * 64 + ln;
      const unsigned d = rk[j] >> 16;
      const unsigned dest = hist[wv * 256 + d] + (rk[j] & 0xFFFFu);
      Kd[dest] = kreg[j];
      Pd[dest] = (pass == 0) ? (unsigned short)e : Ps[e];
    }
    __syncthreads();
  }
  // after 4 passes data is back in Ka / Pa

  // ---- P3: UF init + claim init + inclusion-bit table (coalesced img reads) ----
  for (int t = tid; t < NV; t += NT) parU[Pa[t]] = (unsigned short)(0x8000u | (unsigned)t);
  for (int i = tid; i < NV; i += NT) claim[i] = 0xFFFFFFFFu;
  for (int v = tid; v < NV; v += NT) {
    const unsigned kc = bitsToKey(__float_as_uint(img[v]));
    const int r = v / W_, c = v - r * W_;
    unsigned b = 0;
    if (c > 0       && bitsToKey(__float_as_uint(img[v - 1]))  <= kc) b |= 1u;
    if (c < W_ - 1  && bitsToKey(__float_as_uint(img[v + 1]))  <= kc) b |= 2u;
    if (r > 0       && bitsToKey(__float_as_uint(img[v - W_])) <= kc) b |= 4u;
    if (r < H_ - 1  && bitsToKey(__float_as_uint(img[v + W_])) <= kc) b |= 8u;
    incB[v] = (unsigned char)b;
  }
  __syncthreads();

  // ---- P4: block-wide parallel-commit Kruskal, epoch claims, fully LDS-resident ----
  double T = 0.0, S = 0.0;
  unsigned gr = 0;                                // global round counter (uniform)
  for (int ch = 0; ch < NV / NT; ++ch) {          // 9 chunks
    const int t = ch * NT + tid;
    const int vid = (int)Pa[t];
    const float vt = keyToFloat(Ka[t]);
    const int nv0 = vid - 1, nv1 = vid + 1, nv2 = vid - W_, nv3 = vid + W_;
    const unsigned ib = incB[vid];
    const bool inc0 = (ib & 1u) != 0u;
    const bool inc1 = (ib & 2u) != 0u;
    const bool inc2 = (ib & 4u) != 0u;
    const bool inc3 = (ib & 8u) != 0u;
    int x0 = inc0 ? nv0 : vid, x1 = inc1 ? nv1 : vid;
    int x2 = inc2 ? nv2 : vid, x3 = inc3 ? nv3 : vid;
    unsigned e0 = 0, e1 = 0, e2 = 0, e3 = 0;
    bool committed = false;

    for (;;) {
      const unsigned cval = ((0x000FFFFFu - gr) << 10) | (unsigned)tid;
      ++gr;                                        // uniform across block
      // phase A: re-chase (uncommitted lanes; roots stable in this phase)
      if (!committed) {
        bool d0 = !inc0, d1 = !inc1, d2 = !inc2, d3 = !inc3;
        while (!(d0 && d1 && d2 && d3)) {
          if (!d0) { unsigned e = parU[x0]; if (e & 0x8000u) { e0 = e; d0 = true; } else x0 = (int)e; }
          if (!d1) { unsigned e = parU[x1]; if (e & 0x8000u) { e1 = e; d1 = true; } else x1 = (int)e; }
          if (!d2) { unsigned e = parU[x2]; if (e & 0x8000u) { e2 = e; d2 = true; } else x2 = (int)e; }
          if (!d3) { unsigned e = parU[x3]; if (e & 0x8000u) { e3 = e; d3 = true; } else x3 = (int)e; }
        }
        // path compression (pointer forwarding only; no demotions this phase)
        if (inc0 && nv0 != x0) parU[nv0] = (unsigned short)x0;
        if (inc1 && nv1 != x1) parU[nv1] = (unsigned short)x1;
        if (inc2 && nv2 != x2) parU[nv2] = (unsigned short)x2;
        if (inc3 && nv3 != x3) parU[nv3] = (unsigned short)x3;
      }
      // phase B: survivor, dedupe, claims (epoch value: later rounds always smaller)
      bool u0 = false, u1 = false, u2 = false, u3 = false, uv = false;
      int mvid = vid;
      int rr0 = 0, rr1 = 0, rr2 = 0, rr3 = 0;
      if (!committed) {
        int mrank = t;
        rr0 = (int)(e0 & 0x3FFFu); rr1 = (int)(e1 & 0x3FFFu);
        rr2 = (int)(e2 & 0x3FFFu); rr3 = (int)(e3 & 0x3FFFu);
        if (inc0 && rr0 < mrank) { mrank = rr0; mvid = x0; }
        if (inc1 && rr1 < mrank) { mrank = rr1; mvid = x1; }
        if (inc2 && rr2 < mrank) { mrank = rr2; mvid = x2; }
        if (inc3 && rr3 < mrank) { mrank = rr3; mvid = x3; }
        u0 = inc0 && (x0 != mvid);
        u1 = inc1 && (x1 != mvid) && !(inc0 && x1 == x0);
        u2 = inc2 && (x2 != mvid) && !(inc0 && x2 == x0) && !(inc1 && x2 == x1);
        u3 = inc3 && (x3 != mvid) && !(inc0 && x3 == x0) && !(inc1 && x3 == x1) && !(inc2 && x3 == x2);
        uv = (mvid != vid);
        if (u0) atomicMin(&claim[x0], cval);
        if (u1) atomicMin(&claim[x1], cval);
        if (u2) atomicMin(&claim[x2], cval);
        if (u3) atomicMin(&claim[x3], cval);
        if (uv) atomicMin(&claim[vid], cval);
      }
      __syncthreads();                      // claims visible
      // phase C: win check + commit (claim[] read-only now; parU/K disjoint)
      if (!committed) {
        bool win = true;
        if (u0 && claim[x0] != cval) win = false;
        if (u1 && claim[x1] != cval) win = false;
        if (u2 && claim[x2] != cval) win = false;
        if (u3 && claim[x3] != cval) win = false;
        if (uv && claim[vid] != cval) win = false;
        if (win) {
          if (u0) { const float p = vt - keyToFloat(Ka[rr0]);
                    if (p > 0.0f) { T += (double)p; S += (double)(p * logf(p)); }
                    parU[x0] = (unsigned short)mvid; }
          if (u1) { const float p = vt - keyToFloat(Ka[rr1]);
                    if (p > 0.0f) { T += (double)p; S += (double)(p * logf(p)); }
                    parU[x1] = (unsigned short)mvid; }
          if (u2) { const float p = vt - keyToFloat(Ka[rr2]);
                    if (p > 0.0f) { T += (double)p; S += (double)(p * logf(p)); }
                    parU[x2] = (unsigned short)mvid; }
          if (u3) { const float p = vt - keyToFloat(Ka[rr3]);
                    if (p > 0.0f) { T += (double)p; S += (double)(p * logf(p)); }
                    parU[x3] = (unsigned short)mvid; }
          if (uv) parU[vid] = (unsigned short)mvid;
          committed = true;
        }
      }
      if (__syncthreads_count(!committed ? 1 : 0) == 0) break;  // commits visible
    }
  }

  // ---- P5: block reduction of entropy accumulators ----
  #pragma unroll
  for (int off = 32; off > 0; off >>= 1) {
    T += __shfl_down(T, off, 64);
    S += __shfl_down(S, off, 64);
  }
  if (ln == 0) { Td[wv] = T; Sd[wv] = S; }
  __syncthreads();
  if (tid == 0) {
    double Tt = 0.0, St = 0.0;
    for (int q = 0; q < 16; ++q) { Tt += Td[q]; St += Sd[q]; }
    out[blockIdx.x] = (Tt > 0.0) ? (float)(log(Tt) - St / Tt) : 0.0f;
  }
}

extern "C" void kernel_launch(void* const* d_in, const int* in_sizes, int n_in,
                              void* d_out, int out_size, void* d_ws, size_t ws_size,
                              hipStream_t stream) {
  (void)n_in; (void)out_size; (void)d_ws; (void)ws_size;
  const float* x = (const float*)d_in[0];
  float* out = (float*)d_out;
  int n_img = in_sizes[0] / NV;   // 64
  if (n_img <= 0) n_img = 1;
  topo_pk<<<n_img, NT, 0, stream>>>(x, out);
}